// Round 2
// baseline (2022.994 us; speedup 1.0000x reference)
//
#include <hip/hip_runtime.h>
#include <math.h>

// MultiHeadedAttention with relative position representations (Shaw-style).
// B=4 S=1024 H=1024 NH=16 DK=64 MRP=64 VOCAB=129, fp32 throughout.
//
// Pipeline:
//   1. Q = x@Wq^T+bq, K = x@Wk^T+bk, V = x@Wv^T+bv   (tiled fp32 GEMM)
//   2. flash-style fused attention with rel-pos:
//        logits = QK^T + qr[q][clip(k-q)+64],  qr = Q @ embK^T (per q-tile)
//        out    = P@V + wsum @ embV            (wsum = bucket-sums of P)
//   3. out @ Wo^T + bo
// Workspace: Q,K,V,attn_out = 4 x 16MB = 64MB fp32.

#define TPB 256
constexpr int Bc = 4, Sc = 1024, Hc = 1024, NHc = 16, DKc = 64;
constexpr int NRc = 129;               // 2*MRP+1 rel-pos buckets
constexpr float L2E = 1.44269504088896340736f;

// C[M][N] = A[M][K] @ W[N][K]^T + bias[N]
// 64x64 tile, BK=16, 256 threads, 4x4 microtile per thread.
__global__ __launch_bounds__(TPB) void gemm_bias(
    const float* __restrict__ A, const float* __restrict__ W,
    const float* __restrict__ bias, float* __restrict__ C,
    int M, int N, int Kd) {
  const int tid = threadIdx.x;
  const int tx = tid & 15, ty = tid >> 4;
  const int m0 = blockIdx.y << 6, n0 = blockIdx.x << 6;
  __shared__ float As[64][20];  // stride 20 floats = 80B = 5*16B (b128-aligned rows)
  __shared__ float Ws[64][20];
  float acc[4][4] = {};
  const int lrow = tid >> 2;          // 0..63
  const int lc4 = (tid & 3) << 2;     // 0,4,8,12
  const float* Ap = A + (size_t)(m0 + lrow) * Kd + lc4;
  const float* Wp = W + (size_t)(n0 + lrow) * Kd + lc4;
  for (int kk = 0; kk < Kd; kk += 16) {
    float4 av = *(const float4*)(Ap + kk);
    float4 wv = *(const float4*)(Wp + kk);
    __syncthreads();
    *(float4*)(&As[lrow][lc4]) = av;
    *(float4*)(&Ws[lrow][lc4]) = wv;
    __syncthreads();
#pragma unroll
    for (int c = 0; c < 4; ++c) {
      float4 af[4], wf[4];
#pragma unroll
      for (int i = 0; i < 4; ++i) af[i] = *(const float4*)(&As[ty * 4 + i][c * 4]);
#pragma unroll
      for (int j = 0; j < 4; ++j) wf[j] = *(const float4*)(&Ws[tx * 4 + j][c * 4]);
#pragma unroll
      for (int i = 0; i < 4; ++i)
#pragma unroll
        for (int j = 0; j < 4; ++j)
          acc[i][j] += af[i].x * wf[j].x + af[i].y * wf[j].y +
                       af[i].z * wf[j].z + af[i].w * wf[j].w;
    }
  }
#pragma unroll
  for (int i = 0; i < 4; ++i) {
    const int row = m0 + ty * 4 + i;
    float4 o;
    o.x = acc[i][0] + bias[n0 + tx * 4 + 0];
    o.y = acc[i][1] + bias[n0 + tx * 4 + 1];
    o.z = acc[i][2] + bias[n0 + tx * 4 + 2];
    o.w = acc[i][3] + bias[n0 + tx * 4 + 3];
    *(float4*)(C + (size_t)row * N + n0 + tx * 4) = o;
  }
}

// Fused attention with relative positions.
// grid = (S/64, B*NH); block = 256 (16x16 threads, 4x4 microtile).
// LDS: Qs/Ks/Vs/Ps [64][68] + qr/ws [64][129] + fb[64] = 135,936 B.
__global__ __launch_bounds__(TPB) void attn_rpr(
    const float* __restrict__ Q, const float* __restrict__ K,
    const float* __restrict__ V, const float* __restrict__ eK,
    const float* __restrict__ eV, float* __restrict__ O) {
  __shared__ float smem[4 * 64 * 68 + 2 * 64 * NRc + 64];
  float* Qs = smem;                    // [64][68]
  float* Ks = smem + 64 * 68;          // [64][68]
  float* Vs = smem + 2 * 64 * 68;      // [64][68]
  float* Ps = smem + 3 * 64 * 68;      // [64][68]
  float* qr = smem + 4 * 64 * 68;      // [64][129]  q dot embK
  float* ws = qr + 64 * NRc;           // [64][129]  bucketed P sums
  float* fb = ws + 64 * NRc;           // [64]       per-row rescale factor

  const int tid = threadIdx.x;
  const int tx = tid & 15, ty = tid >> 4;
  const int q0 = blockIdx.x << 6;
  const int bb = (int)blockIdx.y >> 4;
  const int hh = (int)blockIdx.y & 15;
  const size_t base = ((size_t)bb * Sc) * Hc + (size_t)hh * DKc;
  const float* Qp = Q + base;
  const float* Kp = K + base;
  const float* Vp = V + base;

  // stage Q tile; zero ws
  for (int e = tid; e < 64 * 16; e += TPB) {
    int row = e >> 4, c4 = (e & 15) << 2;
    *(float4*)(Qs + row * 68 + c4) =
        *(const float4*)(Qp + (size_t)(q0 + row) * Hc + c4);
  }
  for (int e = tid; e < 64 * NRc; e += TPB) ws[e] = 0.0f;
  __syncthreads();

  // qr[q][r] = dot(Q[q], embK[r])  (embK is 33KB, L1/L2 resident)
  for (int e = tid; e < 64 * NRc; e += TPB) {
    int qq = e / NRc;
    int rr = e - qq * NRc;
    const float4* qv = (const float4*)(Qs + qq * 68);
    const float4* ev = (const float4*)(eK + rr * 64);
    float a = 0.f;
#pragma unroll
    for (int c = 0; c < 16; ++c) {
      float4 xv = qv[c], yv = ev[c];
      a += xv.x * yv.x + xv.y * yv.y + xv.z * yv.z + xv.w * yv.w;
    }
    qr[e] = a;
  }

  float m_[4], l_[4], pLo[4], pHi[4], acc[4][4];
#pragma unroll
  for (int i = 0; i < 4; ++i) {
    m_[i] = -INFINITY; l_[i] = 0.f; pLo[i] = 0.f; pHi[i] = 0.f;
#pragma unroll
    for (int j = 0; j < 4; ++j) acc[i][j] = 0.f;
  }

  for (int kt = 0; kt < Sc / 64; ++kt) {
    const int k0 = kt << 6;
    __syncthreads();  // prior PV / qr-compute done before K/V/P overwrite
    for (int e = tid; e < 64 * 16; e += TPB) {
      int row = e >> 4, c4 = (e & 15) << 2;
      *(float4*)(Ks + row * 68 + c4) =
          *(const float4*)(Kp + (size_t)(k0 + row) * Hc + c4);
      *(float4*)(Vs + row * 68 + c4) =
          *(const float4*)(Vp + (size_t)(k0 + row) * Hc + c4);
    }
    __syncthreads();

    // scores s = Q K^T (64-dot), 4x4 per thread
    float s[4][4];
#pragma unroll
    for (int i = 0; i < 4; ++i)
#pragma unroll
      for (int j = 0; j < 4; ++j) s[i][j] = 0.f;
#pragma unroll
    for (int c = 0; c < 16; ++c) {
      float4 qf[4], kf[4];
#pragma unroll
      for (int i = 0; i < 4; ++i) qf[i] = *(const float4*)(Qs + (ty * 4 + i) * 68 + c * 4);
#pragma unroll
      for (int j = 0; j < 4; ++j) kf[j] = *(const float4*)(Ks + (tx * 4 + j) * 68 + c * 4);
#pragma unroll
      for (int i = 0; i < 4; ++i)
#pragma unroll
        for (int j = 0; j < 4; ++j)
          s[i][j] += qf[i].x * kf[j].x + qf[i].y * kf[j].y +
                     qf[i].z * kf[j].z + qf[i].w * kf[j].w;
    }
    // + rel-K term via qr table
#pragma unroll
    for (int i = 0; i < 4; ++i)
#pragma unroll
      for (int j = 0; j < 4; ++j) {
        int dd = (k0 + tx * 4 + j) - (q0 + ty * 4 + i);
        int bk2 = dd < -64 ? 0 : (dd > 64 ? 128 : dd + 64);
        s[i][j] += qr[(ty * 4 + i) * NRc + bk2];
      }

    // online softmax (row stats across the 16-lane tx group)
    float p[4][4], f[4];
#pragma unroll
    for (int i = 0; i < 4; ++i) {
      float tm = fmaxf(fmaxf(s[i][0], s[i][1]), fmaxf(s[i][2], s[i][3]));
      tm = fmaxf(tm, __shfl_xor(tm, 1));
      tm = fmaxf(tm, __shfl_xor(tm, 2));
      tm = fmaxf(tm, __shfl_xor(tm, 4));
      tm = fmaxf(tm, __shfl_xor(tm, 8));
      float mn = fmaxf(m_[i], tm);
      f[i] = exp2f((m_[i] - mn) * L2E);
      m_[i] = mn;
      float psum = 0.f;
#pragma unroll
      for (int j = 0; j < 4; ++j) {
        p[i][j] = exp2f((s[i][j] - mn) * L2E);
        psum += p[i][j];
      }
      l_[i] = l_[i] * f[i] + psum;
      pLo[i] *= f[i];
      pHi[i] *= f[i];
#pragma unroll
      for (int j = 0; j < 4; ++j) acc[i][j] *= f[i];
#pragma unroll
      for (int j = 0; j < 4; ++j) {  // tail buckets (clip saturation)
        int dd = (k0 + tx * 4 + j) - (q0 + ty * 4 + i);
        if (dd <= -64) pLo[i] += p[i][j];
        else if (dd >= 64) pHi[i] += p[i][j];
      }
      *(float4*)(Ps + (ty * 4 + i) * 68 + tx * 4) =
          make_float4(p[i][0], p[i][1], p[i][2], p[i][3]);
      if (tx == 0) fb[ty * 4 + i] = f[i];
    }
    __syncthreads();
    // rescale bucket sums by this tile's row factors
    for (int e = tid; e < 64 * NRc; e += TPB) {
      int qq = e / NRc;
      ws[e] *= fb[qq];
    }
    __syncthreads();
    // in-band bucket accumulation: bucket = k-q+64 is bijective in k -> race-free
#pragma unroll
    for (int i = 0; i < 4; ++i)
#pragma unroll
      for (int j = 0; j < 4; ++j) {
        int dd = (k0 + tx * 4 + j) - (q0 + ty * 4 + i);
        if (dd > -64 && dd < 64) ws[(ty * 4 + i) * NRc + dd + 64] += p[i][j];
      }
    // PV: acc += P @ V
#pragma unroll
    for (int kc = 0; kc < 16; ++kc) {
      float4 pf[4];
#pragma unroll
      for (int i = 0; i < 4; ++i) pf[i] = *(const float4*)(Ps + (ty * 4 + i) * 68 + kc * 4);
#pragma unroll
      for (int kk = 0; kk < 4; ++kk) {
        float4 vf = *(const float4*)(Vs + (kc * 4 + kk) * 68 + tx * 4);
#pragma unroll
        for (int i = 0; i < 4; ++i) {
          float pv = ((const float*)&pf[i])[kk];  // kk is compile-time (unrolled)
          acc[i][0] += pv * vf.x;
          acc[i][1] += pv * vf.y;
          acc[i][2] += pv * vf.z;
          acc[i][3] += pv * vf.w;
        }
      }
    }
  }

  // reduce row stats across tx group
#pragma unroll
  for (int i = 0; i < 4; ++i) {
    l_[i] += __shfl_xor(l_[i], 1);  l_[i] += __shfl_xor(l_[i], 2);
    l_[i] += __shfl_xor(l_[i], 4);  l_[i] += __shfl_xor(l_[i], 8);
    pLo[i] += __shfl_xor(pLo[i], 1); pLo[i] += __shfl_xor(pLo[i], 2);
    pLo[i] += __shfl_xor(pLo[i], 4); pLo[i] += __shfl_xor(pLo[i], 8);
    pHi[i] += __shfl_xor(pHi[i], 1); pHi[i] += __shfl_xor(pHi[i], 2);
    pHi[i] += __shfl_xor(pHi[i], 4); pHi[i] += __shfl_xor(pHi[i], 8);
  }
  __syncthreads();  // last PV done; safe to overwrite Ks/Vs, finish ws
  if (tx == 0) {
#pragma unroll
    for (int i = 0; i < 4; ++i) {
      ws[(ty * 4 + i) * NRc + 0]   += pLo[i];
      ws[(ty * 4 + i) * NRc + 128] += pHi[i];
    }
  }
  // stage embV (129x64) into Ks..Ps region (8772 floats <= 13056)
  float* eVs = Ks;
  for (int e = tid; e < NRc * 16; e += TPB) {
    int row = e >> 4, c4 = (e & 15) << 2;
    *(float4*)(eVs + row * 68 + c4) = *(const float4*)(eV + row * 64 + c4);
  }
  __syncthreads();
  // acc += ws @ embV  (rel-V term)
  for (int r = 0; r < NRc; ++r) {
    float4 vf = *(const float4*)(eVs + r * 68 + tx * 4);
#pragma unroll
    for (int i = 0; i < 4; ++i) {
      float a = ws[(ty * 4 + i) * NRc + r];
      acc[i][0] += a * vf.x;
      acc[i][1] += a * vf.y;
      acc[i][2] += a * vf.z;
      acc[i][3] += a * vf.w;
    }
  }
  // normalize + store (B,S,H) layout
  float* Op = O + base;
#pragma unroll
  for (int i = 0; i < 4; ++i) {
    float inv = 1.0f / l_[i];
    float4 o = make_float4(acc[i][0] * inv, acc[i][1] * inv,
                           acc[i][2] * inv, acc[i][3] * inv);
    *(float4*)(Op + (size_t)(q0 + ty * 4 + i) * Hc + tx * 4) = o;
  }
}

extern "C" void kernel_launch(void* const* d_in, const int* in_sizes, int n_in,
                              void* d_out, int out_size, void* d_ws, size_t ws_size,
                              hipStream_t stream) {
  const float* x    = (const float*)d_in[0];
  // d_in[1] = mask: dead in reference
  const float* Wq   = (const float*)d_in[2];
  const float* bq   = (const float*)d_in[3];
  const float* Wk   = (const float*)d_in[4];
  const float* bk   = (const float*)d_in[5];
  const float* Wv   = (const float*)d_in[6];
  const float* bv   = (const float*)d_in[7];
  const float* Wo   = (const float*)d_in[8];
  const float* bo   = (const float*)d_in[9];
  const float* embK = (const float*)d_in[10];
  const float* embV = (const float*)d_in[11];
  float* out = (float*)d_out;

  const size_t MxH = (size_t)Bc * Sc * Hc;  // 4,194,304
  float* Qb = (float*)d_ws;                 // 16MB each; needs 64MB workspace
  float* Kb = Qb + MxH;
  float* Vb = Kb + MxH;
  float* Ab = Vb + MxH;

  dim3 gg(Hc / 64, (Bc * Sc) / 64);  // (16, 64)
  gemm_bias<<<gg, TPB, 0, stream>>>(x, Wq, bq, Qb, Bc * Sc, Hc, Hc);
  gemm_bias<<<gg, TPB, 0, stream>>>(x, Wk, bk, Kb, Bc * Sc, Hc, Hc);
  gemm_bias<<<gg, TPB, 0, stream>>>(x, Wv, bv, Vb, Bc * Sc, Hc, Hc);

  dim3 ga(Sc / 64, Bc * NHc);  // (16, 64)
  attn_rpr<<<ga, TPB, 0, stream>>>(Qb, Kb, Vb, embK, embV, Ab);

  gemm_bias<<<gg, TPB, 0, stream>>>(Ab, Wo, bo, out, Bc * Sc, Hc, Hc);
}

// Round 3
// 1731.542 us; speedup vs baseline: 1.1683x; 1.1683x over previous
//
#include <hip/hip_runtime.h>
#include <math.h>

// MultiHeadedAttention with relative position representations (Shaw-style).
// B=4 S=1024 H=1024 NH=16 DK=64 MRP=64 VOCAB=129, fp32 in/out.
//
// Pipeline:
//   1. Q/K/V/out projections: split-bf16 ("bf16x3") MFMA GEMM, fp32-equivalent
//      precision: a=ah+al, w=wh+wl -> C = al*wh + ah*wl + ah*wh (3 mfma).
//   2. flash-style fused fp32 attention with rel-pos tables (qr, ws buckets),
//      band-specialized: only k-tiles |kt-qt|<=1 need per-element rel handling.
// Workspace: Q,K,V,attn_out = 4 x 16MB = 64MB fp32.

#define TPB 256
constexpr int Bc = 4, Sc = 1024, Hc = 1024, NHc = 16, DKc = 64;
constexpr int NRc = 129;               // 2*MRP+1 rel-pos buckets
constexpr float L2E = 1.44269504088896340736f;

using bf16x8 = __attribute__((ext_vector_type(8))) short;
using f32x4v = __attribute__((ext_vector_type(4))) float;

__device__ inline unsigned short f2bf(float f) {      // RNE fp32 -> bf16 bits
  unsigned int u = __float_as_uint(f);
  return (unsigned short)((u + 0x7FFFu + ((u >> 16) & 1u)) >> 16);
}
__device__ inline float bf2f(unsigned short h) {
  return __uint_as_float(((unsigned int)h) << 16);
}

// ---------------------------------------------------------------------------
// C[M][N] = A[M][K] @ W[N][K]^T + bias[N], split-bf16 MFMA (3 products).
// BM=128 BN=64 BK=32, 256 threads (4 waves, 2x2 wave grid, wave tile 64x32).
// grid = (N/64, M/128).
__global__ __launch_bounds__(TPB) void gemm_mfma3(
    const float* __restrict__ A, const float* __restrict__ W,
    const float* __restrict__ bias, float* __restrict__ C,
    int M, int N, int Kd) {
  __shared__ unsigned short Ah[128 * 32], Al[128 * 32];
  __shared__ unsigned short Bh[64 * 32],  Bl[64 * 32];   // 24 KB total

  const int tid = threadIdx.x;
  const int lane = tid & 63, wid = tid >> 6;
  const int wr = wid >> 1, wc = wid & 1;
  const int m0 = blockIdx.y * 128, n0 = blockIdx.x * 64;
  const int fr = lane & 15, fg = lane >> 4;

  // staging assignment: A: 16 f32/thread, B: 8 f32/thread
  const int ar = tid >> 1, akb = (tid & 1) * 16;
  const int br = tid >> 2, bkb = (tid & 3) * 8;
  const float* Ap = A + (size_t)(m0 + ar) * Kd + akb;
  const float* Bp = W + (size_t)(n0 + br) * Kd + bkb;

  f32x4v acc[4][2];
#pragma unroll
  for (int i = 0; i < 4; ++i)
#pragma unroll
    for (int j = 0; j < 2; ++j) acc[i][j] = (f32x4v)(0.f);

  float4 ra[4], rb[2];
#pragma unroll
  for (int q = 0; q < 4; ++q) ra[q] = *(const float4*)(Ap + q * 4);
#pragma unroll
  for (int q = 0; q < 2; ++q) rb[q] = *(const float4*)(Bp + q * 4);

  const int nK = Kd / 32;
  for (int kt = 0; kt < nK; ++kt) {
    __syncthreads();  // previous compute done; LDS reusable
    // write staged regs -> LDS as bf16 hi/lo
#pragma unroll
    for (int q = 0; q < 2; ++q) {
      bf16x8 vh, vl;
#pragma unroll
      for (int e = 0; e < 8; ++e) {
        float v = ((const float*)ra)[q * 8 + e];
        unsigned short h = f2bf(v);
        vh[e] = (short)h;
        vl[e] = (short)f2bf(v - bf2f(h));
      }
      *(bf16x8*)(&Ah[ar * 32 + akb + q * 8]) = vh;
      *(bf16x8*)(&Al[ar * 32 + akb + q * 8]) = vl;
    }
    {
      bf16x8 vh, vl;
#pragma unroll
      for (int e = 0; e < 8; ++e) {
        float v = ((const float*)rb)[e];
        unsigned short h = f2bf(v);
        vh[e] = (short)h;
        vl[e] = (short)f2bf(v - bf2f(h));
      }
      *(bf16x8*)(&Bh[br * 32 + bkb]) = vh;
      *(bf16x8*)(&Bl[br * 32 + bkb]) = vl;
    }
    __syncthreads();
    if (kt + 1 < nK) {  // prefetch next K-slab; latency hides under mfma
      const float* Ap2 = Ap + (kt + 1) * 32;
      const float* Bp2 = Bp + (kt + 1) * 32;
#pragma unroll
      for (int q = 0; q < 4; ++q) ra[q] = *(const float4*)(Ap2 + q * 4);
#pragma unroll
      for (int q = 0; q < 2; ++q) rb[q] = *(const float4*)(Bp2 + q * 4);
    }
    // fragments: A row = lane&15 (+16*mf), k = (lane>>4)*8..+7
    bf16x8 fah[4], fal[4], fbh[2], fbl[2];
#pragma unroll
    for (int mf = 0; mf < 4; ++mf) {
      int r = wr * 64 + mf * 16 + fr;
      fah[mf] = *(const bf16x8*)(&Ah[r * 32 + fg * 8]);
      fal[mf] = *(const bf16x8*)(&Al[r * 32 + fg * 8]);
    }
#pragma unroll
    for (int nf = 0; nf < 2; ++nf) {
      int r = wc * 32 + nf * 16 + fr;
      fbh[nf] = *(const bf16x8*)(&Bh[r * 32 + fg * 8]);
      fbl[nf] = *(const bf16x8*)(&Bl[r * 32 + fg * 8]);
    }
#pragma unroll
    for (int mf = 0; mf < 4; ++mf)
#pragma unroll
      for (int nf = 0; nf < 2; ++nf) {
        acc[mf][nf] = __builtin_amdgcn_mfma_f32_16x16x32_bf16(
            fal[mf], fbh[nf], acc[mf][nf], 0, 0, 0);
        acc[mf][nf] = __builtin_amdgcn_mfma_f32_16x16x32_bf16(
            fah[mf], fbl[nf], acc[mf][nf], 0, 0, 0);
        acc[mf][nf] = __builtin_amdgcn_mfma_f32_16x16x32_bf16(
            fah[mf], fbh[nf], acc[mf][nf], 0, 0, 0);
      }
  }

  // epilogue: D row=(lane>>4)*4+reg, col=lane&15 (m89-verified)
#pragma unroll
  for (int nf = 0; nf < 2; ++nf) {
    int col = n0 + wc * 32 + nf * 16 + fr;
    float bv = bias[col];
#pragma unroll
    for (int mf = 0; mf < 4; ++mf)
#pragma unroll
      for (int rg = 0; rg < 4; ++rg) {
        int row = m0 + wr * 64 + mf * 16 + fg * 4 + rg;
        C[(size_t)row * N + col] = acc[mf][nf][rg] + bv;
      }
  }
}

// ---------------------------------------------------------------------------
// Fused attention with relative positions (fp32).
// grid = (S/64, B*NH); block = 256 (16x16 threads, 4x4 microtile).
// Score-column mapping: col = j*16 + tx (conflict-free Ks frag reads).
// PV/output-dim mapping: d = tx*4 + j (unchanged, conflict-free).
__global__ __launch_bounds__(TPB) void attn_rpr(
    const float* __restrict__ Q, const float* __restrict__ K,
    const float* __restrict__ V, const float* __restrict__ eK,
    const float* __restrict__ eV, float* __restrict__ O) {
  __shared__ float smem[4 * 64 * 68 + 2 * 64 * NRc + 64];
  float* Qs = smem;                    // [64][68]
  float* Ks = smem + 64 * 68;          // [64][68]
  float* Vs = smem + 2 * 64 * 68;      // [64][68]
  float* Ps = smem + 3 * 64 * 68;      // [64][68]
  float* qr = smem + 4 * 64 * 68;      // [64][129]  q dot embK
  float* ws = qr + 64 * NRc;           // [64][129]  bucketed P sums
  float* fb = ws + 64 * NRc;           // [64]       per-row rescale factor

  const int tid = threadIdx.x;
  const int tx = tid & 15, ty = tid >> 4;
  const int qt = blockIdx.x;
  const int q0 = qt << 6;
  const int bb = (int)blockIdx.y >> 4;
  const int hh = (int)blockIdx.y & 15;
  const size_t base = ((size_t)bb * Sc) * Hc + (size_t)hh * DKc;
  const float* Qp = Q + base;
  const float* Kp = K + base;
  const float* Vp = V + base;

  for (int e = tid; e < 64 * 16; e += TPB) {
    int row = e >> 4, c4 = (e & 15) << 2;
    *(float4*)(Qs + row * 68 + c4) =
        *(const float4*)(Qp + (size_t)(q0 + row) * Hc + c4);
  }
  for (int e = tid; e < 64 * NRc; e += TPB) ws[e] = 0.0f;
  __syncthreads();

  // qr[q][r] = dot(Q[q], embK[r])
  for (int e = tid; e < 64 * NRc; e += TPB) {
    int qq = e / NRc;
    int rr = e - qq * NRc;
    const float4* qv = (const float4*)(Qs + qq * 68);
    const float4* ev = (const float4*)(eK + rr * 64);
    float a = 0.f;
#pragma unroll
    for (int c = 0; c < 16; ++c) {
      float4 xv = qv[c], yv = ev[c];
      a += xv.x * yv.x + xv.y * yv.y + xv.z * yv.z + xv.w * yv.w;
    }
    qr[e] = a;
  }
  __syncthreads();
  // per-row saturated-bucket constants in regs
  float qr0r[4], qr128r[4];
#pragma unroll
  for (int i = 0; i < 4; ++i) {
    qr0r[i] = qr[(ty * 4 + i) * NRc + 0];
    qr128r[i] = qr[(ty * 4 + i) * NRc + 128];
  }

  float m_[4], l_[4], pLo[4], pHi[4], acc[4][4];
#pragma unroll
  for (int i = 0; i < 4; ++i) {
    m_[i] = -INFINITY; l_[i] = 0.f; pLo[i] = 0.f; pHi[i] = 0.f;
#pragma unroll
    for (int j = 0; j < 4; ++j) acc[i][j] = 0.f;
  }

  for (int kt = 0; kt < Sc / 64; ++kt) {
    const int k0 = kt << 6;
    const int band = kt - qt;                 // block-uniform
    const bool inband = (band >= -1) && (band <= 1);
    __syncthreads();  // prior PV / table ops done before K/V/P overwrite
    for (int e = tid; e < 64 * 16; e += TPB) {
      int row = e >> 4, c4 = (e & 15) << 2;
      *(float4*)(Ks + row * 68 + c4) =
          *(const float4*)(Kp + (size_t)(k0 + row) * Hc + c4);
      *(float4*)(Vs + row * 68 + c4) =
          *(const float4*)(Vp + (size_t)(k0 + row) * Hc + c4);
    }
    __syncthreads();

    // s[i][j]: score for q-row (q0+ty*4+i), k-col (k0+j*16+tx)
    float s[4][4];
#pragma unroll
    for (int i = 0; i < 4; ++i)
#pragma unroll
      for (int j = 0; j < 4; ++j) s[i][j] = 0.f;
#pragma unroll
    for (int c = 0; c < 16; ++c) {
      float4 qf[4], kf[4];
#pragma unroll
      for (int i = 0; i < 4; ++i)
        qf[i] = *(const float4*)(Qs + (ty * 4 + i) * 68 + c * 4);
#pragma unroll
      for (int j = 0; j < 4; ++j)
        kf[j] = *(const float4*)(Ks + (j * 16 + tx) * 68 + c * 4);
#pragma unroll
      for (int i = 0; i < 4; ++i)
#pragma unroll
        for (int j = 0; j < 4; ++j)
          s[i][j] += qf[i].x * kf[j].x + qf[i].y * kf[j].y +
                     qf[i].z * kf[j].z + qf[i].w * kf[j].w;
    }
    // rel-K term
    if (inband) {
#pragma unroll
      for (int i = 0; i < 4; ++i)
#pragma unroll
        for (int j = 0; j < 4; ++j) {
          int dd = (k0 + j * 16 + tx) - (q0 + ty * 4 + i);
          int bk2 = dd < -64 ? 0 : (dd > 64 ? 128 : dd + 64);
          s[i][j] += qr[(ty * 4 + i) * NRc + bk2];
        }
    } else {
#pragma unroll
      for (int i = 0; i < 4; ++i) {
        float qc = (band < 0) ? qr0r[i] : qr128r[i];
#pragma unroll
        for (int j = 0; j < 4; ++j) s[i][j] += qc;
      }
    }

    // online softmax (row stats across 16-lane tx group)
    float p[4][4], f[4];
#pragma unroll
    for (int i = 0; i < 4; ++i) {
      float tm = fmaxf(fmaxf(s[i][0], s[i][1]), fmaxf(s[i][2], s[i][3]));
      tm = fmaxf(tm, __shfl_xor(tm, 1));
      tm = fmaxf(tm, __shfl_xor(tm, 2));
      tm = fmaxf(tm, __shfl_xor(tm, 4));
      tm = fmaxf(tm, __shfl_xor(tm, 8));
      float mn = fmaxf(m_[i], tm);
      f[i] = exp2f((m_[i] - mn) * L2E);
      m_[i] = mn;
      float psum = 0.f;
#pragma unroll
      for (int j = 0; j < 4; ++j) {
        p[i][j] = exp2f((s[i][j] - mn) * L2E);
        psum += p[i][j];
      }
      l_[i] = l_[i] * f[i] + psum;
      pLo[i] *= f[i];
      pHi[i] *= f[i];
#pragma unroll
      for (int j = 0; j < 4; ++j) acc[i][j] *= f[i];
      if (inband) {
#pragma unroll
        for (int j = 0; j < 4; ++j) {  // boundary tails
          int dd = (k0 + j * 16 + tx) - (q0 + ty * 4 + i);
          if (dd <= -64) pLo[i] += p[i][j];
          else if (dd >= 64) pHi[i] += p[i][j];
        }
      } else if (band < 0) {
        pLo[i] += psum;
      } else {
        pHi[i] += psum;
      }
      // P -> LDS (scalar stores; 2-way max on banks)
#pragma unroll
      for (int j = 0; j < 4; ++j)
        Ps[(ty * 4 + i) * 68 + j * 16 + tx] = p[i][j];
      if (tx == 0) fb[ty * 4 + i] = f[i];
    }
    __syncthreads();  // Ps complete; fb complete
    if (kt > 0 && kt >= qt) {  // ws nonzero from tile qt-1 onward
      for (int e = tid; e < 64 * NRc; e += TPB) ws[e] *= fb[e / NRc];
      __syncthreads();
    }
    if (inband) {
      // bucket accumulation: bucket <-> k bijective per row -> race-free
#pragma unroll
      for (int i = 0; i < 4; ++i)
#pragma unroll
        for (int j = 0; j < 4; ++j) {
          int dd = (k0 + j * 16 + tx) - (q0 + ty * 4 + i);
          if (dd > -64 && dd < 64)
            ws[(ty * 4 + i) * NRc + dd + 64] += p[i][j];
        }
    }
    // PV: acc += P @ V   (output dim d = tx*4 + j)
#pragma unroll
    for (int kc = 0; kc < 16; ++kc) {
      float4 pf[4];
#pragma unroll
      for (int i = 0; i < 4; ++i)
        pf[i] = *(const float4*)(Ps + (ty * 4 + i) * 68 + kc * 4);
#pragma unroll
      for (int kk = 0; kk < 4; ++kk) {
        float4 vf = *(const float4*)(Vs + (kc * 4 + kk) * 68 + tx * 4);
#pragma unroll
        for (int i = 0; i < 4; ++i) {
          float pv = ((const float*)&pf[i])[kk];  // compile-time idx
          acc[i][0] += pv * vf.x;
          acc[i][1] += pv * vf.y;
          acc[i][2] += pv * vf.z;
          acc[i][3] += pv * vf.w;
        }
      }
    }
  }

  // reduce row stats across tx group
#pragma unroll
  for (int i = 0; i < 4; ++i) {
    l_[i] += __shfl_xor(l_[i], 1);  l_[i] += __shfl_xor(l_[i], 2);
    l_[i] += __shfl_xor(l_[i], 4);  l_[i] += __shfl_xor(l_[i], 8);
    pLo[i] += __shfl_xor(pLo[i], 1); pLo[i] += __shfl_xor(pLo[i], 2);
    pLo[i] += __shfl_xor(pLo[i], 4); pLo[i] += __shfl_xor(pLo[i], 8);
    pHi[i] += __shfl_xor(pHi[i], 1); pHi[i] += __shfl_xor(pHi[i], 2);
    pHi[i] += __shfl_xor(pHi[i], 4); pHi[i] += __shfl_xor(pHi[i], 8);
  }
  __syncthreads();  // last PV done; safe to finish ws, overwrite Ks
  if (tx == 0) {
#pragma unroll
    for (int i = 0; i < 4; ++i) {
      ws[(ty * 4 + i) * NRc + 0]   += pLo[i];
      ws[(ty * 4 + i) * NRc + 128] += pHi[i];
    }
  }
  // stage embV into Ks region
  float* eVs = Ks;
  for (int e = tid; e < NRc * 16; e += TPB) {
    int row = e >> 4, c4 = (e & 15) << 2;
    *(float4*)(eVs + row * 68 + c4) = *(const float4*)(eV + row * 64 + c4);
  }
  __syncthreads();
  // acc += ws @ embV
  for (int r = 0; r < NRc; ++r) {
    float4 vf = *(const float4*)(eVs + r * 68 + tx * 4);
#pragma unroll
    for (int i = 0; i < 4; ++i) {
      float a = ws[(ty * 4 + i) * NRc + r];
      acc[i][0] += a * vf.x;
      acc[i][1] += a * vf.y;
      acc[i][2] += a * vf.z;
      acc[i][3] += a * vf.w;
    }
  }
  // normalize + store (B,S,H)
  float* Op = O + base;
#pragma unroll
  for (int i = 0; i < 4; ++i) {
    float inv = 1.0f / l_[i];
    float4 o = make_float4(acc[i][0] * inv, acc[i][1] * inv,
                           acc[i][2] * inv, acc[i][3] * inv);
    *(float4*)(Op + (size_t)(q0 + ty * 4 + i) * Hc + tx * 4) = o;
  }
}

extern "C" void kernel_launch(void* const* d_in, const int* in_sizes, int n_in,
                              void* d_out, int out_size, void* d_ws, size_t ws_size,
                              hipStream_t stream) {
  const float* x    = (const float*)d_in[0];
  // d_in[1] = mask: dead in reference
  const float* Wq   = (const float*)d_in[2];
  const float* bq   = (const float*)d_in[3];
  const float* Wk   = (const float*)d_in[4];
  const float* bk   = (const float*)d_in[5];
  const float* Wv   = (const float*)d_in[6];
  const float* bv   = (const float*)d_in[7];
  const float* Wo   = (const float*)d_in[8];
  const float* bo   = (const float*)d_in[9];
  const float* embK = (const float*)d_in[10];
  const float* embV = (const float*)d_in[11];
  float* out = (float*)d_out;

  const size_t MxH = (size_t)Bc * Sc * Hc;  // 4,194,304
  float* Qb = (float*)d_ws;                 // 64MB workspace
  float* Kb = Qb + MxH;
  float* Vb = Kb + MxH;
  float* Ab = Vb + MxH;

  dim3 gg(Hc / 64, (Bc * Sc) / 128);  // (16, 32)
  gemm_mfma3<<<gg, TPB, 0, stream>>>(x, Wq, bq, Qb, Bc * Sc, Hc, Hc);
  gemm_mfma3<<<gg, TPB, 0, stream>>>(x, Wk, bk, Kb, Bc * Sc, Hc, Hc);
  gemm_mfma3<<<gg, TPB, 0, stream>>>(x, Wv, bv, Vb, Bc * Sc, Hc, Hc);

  dim3 ga(Sc / 64, Bc * NHc);  // (16, 64)
  attn_rpr<<<ga, TPB, 0, stream>>>(Qb, Kb, Vb, embK, embV, Ab);

  gemm_mfma3<<<gg, TPB, 0, stream>>>(Ab, Wo, bo, out, Bc * Sc, Hc, Hc);
}

// Round 4
// 849.787 us; speedup vs baseline: 2.3806x; 2.0376x over previous
//
#include <hip/hip_runtime.h>
#include <math.h>

// MultiHeadedAttention with relative position representations (Shaw-style).
// B=4 S=1024 H=1024 NH=16 DK=64 MRP=64 VOCAB=129, fp32 in/out.
//
// Pipeline:
//   1. Q/K/V/out projections: split-bf16 ("bf16x3") MFMA GEMM.
//   2. MFMA flash attention: QK^T and PV both split-bf16 x3 (fp32-equivalent).
//      rel-K via qr table lookup; rel-V via deferred-rescale bucket table ws
//      (in-band P written once, corrected by exp(m_tile - m_final) at end).
// Workspace: Q,K,V,attn_out = 4 x 16MB = 64MB fp32.

#define TPB 256
constexpr int Bc = 4, Sc = 1024, Hc = 1024, NHc = 16, DKc = 64;
constexpr int NRc = 129;               // 2*MRP+1 rel-pos buckets
constexpr float L2E = 1.44269504088896340736f;

using bf16x8 = __attribute__((ext_vector_type(8))) short;
using f32x4v = __attribute__((ext_vector_type(4))) float;

__device__ inline unsigned short f2bf(float f) {      // RNE fp32 -> bf16 bits
  unsigned int u = __float_as_uint(f);
  return (unsigned short)((u + 0x7FFFu + ((u >> 16) & 1u)) >> 16);
}
__device__ inline float bf2f(unsigned short h) {
  return __uint_as_float(((unsigned int)h) << 16);
}

// ---------------------------------------------------------------------------
// C[M][N] = A[M][K] @ W[N][K]^T + bias[N], split-bf16 MFMA (3 products).
// BM=128 BN=64 BK=32, 256 threads (4 waves, 2x2 wave grid, wave tile 64x32).
__global__ __launch_bounds__(TPB) void gemm_mfma3(
    const float* __restrict__ A, const float* __restrict__ W,
    const float* __restrict__ bias, float* __restrict__ C,
    int M, int N, int Kd) {
  __shared__ unsigned short Ah[128 * 32], Al[128 * 32];
  __shared__ unsigned short Bh[64 * 32],  Bl[64 * 32];   // 24 KB total

  const int tid = threadIdx.x;
  const int lane = tid & 63, wid = tid >> 6;
  const int wr = wid >> 1, wc = wid & 1;
  const int m0 = blockIdx.y * 128, n0 = blockIdx.x * 64;
  const int fr = lane & 15, fg = lane >> 4;

  const int ar = tid >> 1, akb = (tid & 1) * 16;
  const int br = tid >> 2, bkb = (tid & 3) * 8;
  const float* Ap = A + (size_t)(m0 + ar) * Kd + akb;
  const float* Bp = W + (size_t)(n0 + br) * Kd + bkb;

  f32x4v acc[4][2];
#pragma unroll
  for (int i = 0; i < 4; ++i)
#pragma unroll
    for (int j = 0; j < 2; ++j) acc[i][j] = (f32x4v)(0.f);

  float4 ra[4], rb[2];
#pragma unroll
  for (int q = 0; q < 4; ++q) ra[q] = *(const float4*)(Ap + q * 4);
#pragma unroll
  for (int q = 0; q < 2; ++q) rb[q] = *(const float4*)(Bp + q * 4);

  const int nK = Kd / 32;
  for (int kt = 0; kt < nK; ++kt) {
    __syncthreads();
#pragma unroll
    for (int q = 0; q < 2; ++q) {
      bf16x8 vh, vl;
#pragma unroll
      for (int e = 0; e < 8; ++e) {
        float v = ((const float*)ra)[q * 8 + e];
        unsigned short h = f2bf(v);
        vh[e] = (short)h;
        vl[e] = (short)f2bf(v - bf2f(h));
      }
      *(bf16x8*)(&Ah[ar * 32 + akb + q * 8]) = vh;
      *(bf16x8*)(&Al[ar * 32 + akb + q * 8]) = vl;
    }
    {
      bf16x8 vh, vl;
#pragma unroll
      for (int e = 0; e < 8; ++e) {
        float v = ((const float*)rb)[e];
        unsigned short h = f2bf(v);
        vh[e] = (short)h;
        vl[e] = (short)f2bf(v - bf2f(h));
      }
      *(bf16x8*)(&Bh[br * 32 + bkb]) = vh;
      *(bf16x8*)(&Bl[br * 32 + bkb]) = vl;
    }
    __syncthreads();
    if (kt + 1 < nK) {
      const float* Ap2 = Ap + (kt + 1) * 32;
      const float* Bp2 = Bp + (kt + 1) * 32;
#pragma unroll
      for (int q = 0; q < 4; ++q) ra[q] = *(const float4*)(Ap2 + q * 4);
#pragma unroll
      for (int q = 0; q < 2; ++q) rb[q] = *(const float4*)(Bp2 + q * 4);
    }
    bf16x8 fah[4], fal[4], fbh[2], fbl[2];
#pragma unroll
    for (int mf = 0; mf < 4; ++mf) {
      int r = wr * 64 + mf * 16 + fr;
      fah[mf] = *(const bf16x8*)(&Ah[r * 32 + fg * 8]);
      fal[mf] = *(const bf16x8*)(&Al[r * 32 + fg * 8]);
    }
#pragma unroll
    for (int nf = 0; nf < 2; ++nf) {
      int r = wc * 32 + nf * 16 + fr;
      fbh[nf] = *(const bf16x8*)(&Bh[r * 32 + fg * 8]);
      fbl[nf] = *(const bf16x8*)(&Bl[r * 32 + fg * 8]);
    }
#pragma unroll
    for (int mf = 0; mf < 4; ++mf)
#pragma unroll
      for (int nf = 0; nf < 2; ++nf) {
        acc[mf][nf] = __builtin_amdgcn_mfma_f32_16x16x32_bf16(
            fal[mf], fbh[nf], acc[mf][nf], 0, 0, 0);
        acc[mf][nf] = __builtin_amdgcn_mfma_f32_16x16x32_bf16(
            fah[mf], fbl[nf], acc[mf][nf], 0, 0, 0);
        acc[mf][nf] = __builtin_amdgcn_mfma_f32_16x16x32_bf16(
            fah[mf], fbh[nf], acc[mf][nf], 0, 0, 0);
      }
  }
#pragma unroll
  for (int nf = 0; nf < 2; ++nf) {
    int col = n0 + wc * 32 + nf * 16 + fr;
    float bv = bias[col];
#pragma unroll
    for (int mf = 0; mf < 4; ++mf)
#pragma unroll
      for (int rg = 0; rg < 4; ++rg) {
        int row = m0 + wr * 64 + mf * 16 + fg * 4 + rg;
        C[(size_t)row * N + col] = acc[mf][nf][rg] + bv;
      }
  }
}

// ---------------------------------------------------------------------------
// MFMA fused attention with relative positions.
// grid = (S/64, B*NH); block = 256 = 4 waves, wave w owns q-rows w*16..w*16+15.
// mfma 16x16x32 bf16; QK^T and PV both split-bf16 (3 mfma per product).
// D layout (m89): col=lane&15, row=(lane>>4)*4+reg -> stats rows per lane
// identical for QK output (q-rows) and PV output (q-rows).
__global__ __launch_bounds__(TPB, 1) void attn_mfma(
    const float* __restrict__ Q, const float* __restrict__ K,
    const float* __restrict__ V, const float* __restrict__ eK,
    const float* __restrict__ eV, float* __restrict__ O) {
  // LDS map (bytes):
  //  KsH 0..9216       [64][72] bf16 hi      (pad-72: frag reads at b128 floor)
  //  KsL 9216          [64][72] bf16 lo
  //  VtH 18432         [64][64] bf16 hi, XOR-swizzled (^(d&7)<<3 on ushort idx)
  //  VtL 26624         [64][64] bf16 lo, swizzled
  //  PsH 34816         [64][72] bf16 hi (wave-private rows)
  //  PsL 44032         [64][72] bf16 lo
  //  Vf  53248         [64][68] f32 (staging for V transpose)
  //  qr  70656         [64][129] f32   (Q . embK, also reused as Qs staging? no)
  //  ws  103680        [64][129] f32   (bucket P table; Qs staging overlay)
  //  mhist 136704      [3][64] f32
  //  mfin  137472      [64] f32
  __shared__ __align__(16) unsigned char smem[137728];
  unsigned short* KsH = (unsigned short*)(smem);
  unsigned short* KsL = (unsigned short*)(smem + 9216);
  unsigned short* VtH = (unsigned short*)(smem + 18432);
  unsigned short* VtL = (unsigned short*)(smem + 26624);
  unsigned short* PsH = (unsigned short*)(smem + 34816);
  unsigned short* PsL = (unsigned short*)(smem + 44032);
  float* Vf    = (float*)(smem + 53248);
  float* qr    = (float*)(smem + 70656);
  float* ws    = (float*)(smem + 103680);
  float* mhist = (float*)(smem + 136704);
  float* mfin  = (float*)(smem + 137472);

  const int tid = threadIdx.x;
  const int lane = tid & 63, w = tid >> 6;
  const int fr = lane & 15, g = lane >> 4;
  const int qt = blockIdx.x, q0 = qt << 6;
  const int bb = (int)blockIdx.y >> 4, hh = (int)blockIdx.y & 15;
  const size_t base = ((size_t)bb * Sc) * Hc + (size_t)hh * DKc;
  const float* Qp = Q + base;
  const float* Kp = K + base;
  const float* Vp = V + base;

  // ---- prologue: stage Q fp32 into ws region, compute qr ----
  float* Qs = ws;  // [64][66] overlay, dead after qr compute
  {
    const int row = tid >> 2, c0 = (tid & 3) << 4;
    const float* src = Qp + (size_t)(q0 + row) * Hc + c0;
#pragma unroll
    for (int q = 0; q < 4; ++q)
      *(float4*)(Qs + row * 66 + c0 + q * 4) = *(const float4*)(src + q * 4);
  }
  if (tid < 192) mhist[tid] = -INFINITY;
  __syncthreads();
  for (int e = tid; e < 64 * NRc; e += TPB) {
    const int row = e / NRc, rr = e - row * NRc;
    const float* qv = Qs + row * 66;
    const float* ev = eK + rr * 64;
    float a = 0.f;
#pragma unroll
    for (int c = 0; c < 16; ++c) {
      float4 x = *(const float4*)(qv + c * 4);
      float4 y = *(const float4*)(ev + c * 4);
      a += x.x * y.x + x.y * y.y + x.z * y.z + x.w * y.w;
    }
    qr[e] = a;
  }
  __syncthreads();  // qr ready; Qs (ws region) reusable

  for (int e = tid; e < 64 * NRc; e += TPB) ws[e] = 0.0f;

  // Q fragments (global -> bf16 hi/lo regs), A-frag: row=lane&15, k=g*8+e
  bf16x8 qh[2], ql[2];
#pragma unroll
  for (int ks = 0; ks < 2; ++ks) {
    const float* qsrc = Qp + (size_t)(q0 + w * 16 + fr) * Hc + ks * 32 + g * 8;
    float4 x0 = *(const float4*)(qsrc);
    float4 x1 = *(const float4*)(qsrc + 4);
    float xv[8] = {x0.x, x0.y, x0.z, x0.w, x1.x, x1.y, x1.z, x1.w};
#pragma unroll
    for (int e = 0; e < 8; ++e) {
      const unsigned short hb = f2bf(xv[e]);
      qh[ks][e] = (short)hb;
      ql[ks][e] = (short)f2bf(xv[e] - bf2f(hb));
    }
  }
  float qr0r[4], qr128r[4];
#pragma unroll
  for (int r = 0; r < 4; ++r) {
    qr0r[r]   = qr[(w * 16 + g * 4 + r) * NRc + 0];
    qr128r[r] = qr[(w * 16 + g * 4 + r) * NRc + 128];
  }

  float m_[4], l_[4], pLo[4], pHi[4];
  f32x4v accO[4];
#pragma unroll
  for (int r = 0; r < 4; ++r) { m_[r] = -INFINITY; l_[r] = 0.f; pLo[r] = 0.f; pHi[r] = 0.f; }
#pragma unroll
  for (int dt = 0; dt < 4; ++dt) accO[dt] = (f32x4v)(0.f);

  // staging regs for K/V tile (reg-staged, loads issued a tile ahead)
  const int srow = tid >> 2, sc0 = (tid & 3) << 4;
  float4 rk[4], rv[4];
#pragma unroll
  for (int q = 0; q < 4; ++q) {
    rk[q] = *(const float4*)(Kp + (size_t)srow * Hc + sc0 + q * 4);
    rv[q] = *(const float4*)(Vp + (size_t)srow * Hc + sc0 + q * 4);
  }
  __syncthreads();  // ws zeroed (and qr consts read)

  // ---- main loop over k-tiles ----
  for (int kt = 0; kt < Sc / 64; ++kt) {
    const int k0 = kt << 6;
    const int band = kt - qt;
    const bool inband = (band >= -1) && (band <= 1);
    if (kt) __syncthreads();  // barrier1: prior tile fully consumed

    // K regs -> bf16 hi/lo LDS; V regs -> fp32 staging
    {
      bf16x8 h0, h1, l0, l1;
#pragma unroll
      for (int e = 0; e < 8; ++e) {
        float v0 = ((const float*)rk)[e];
        float v1 = ((const float*)rk)[8 + e];
        unsigned short a = f2bf(v0); h0[e] = (short)a; l0[e] = (short)f2bf(v0 - bf2f(a));
        unsigned short b = f2bf(v1); h1[e] = (short)b; l1[e] = (short)f2bf(v1 - bf2f(b));
      }
      *(bf16x8*)(&KsH[srow * 72 + sc0])     = h0;
      *(bf16x8*)(&KsH[srow * 72 + sc0 + 8]) = h1;
      *(bf16x8*)(&KsL[srow * 72 + sc0])     = l0;
      *(bf16x8*)(&KsL[srow * 72 + sc0 + 8]) = l1;
#pragma unroll
      for (int q = 0; q < 4; ++q)
        *(float4*)(Vf + srow * 68 + sc0 + q * 4) = rv[q];
    }
    if (kt + 1 < Sc / 64) {  // prefetch next tile into regs (hides under compute)
      const int kn = (kt + 1) << 6;
#pragma unroll
      for (int q = 0; q < 4; ++q) {
        rk[q] = *(const float4*)(Kp + (size_t)(kn + srow) * Hc + sc0 + q * 4);
        rv[q] = *(const float4*)(Vp + (size_t)(kn + srow) * Hc + sc0 + q * 4);
      }
    }
    __syncthreads();  // barrier2: Ks + Vf ready

    // transpose V: Vf[k][d] -> VtH/VtL[d][k] (swizzled), b128 writes
    {
      const int d = tid & 63, kb = (tid >> 6) << 4;
      float vv[16];
#pragma unroll
      for (int j = 0; j < 16; ++j) vv[j] = Vf[(kb + j) * 68 + d];
      bf16x8 th0, th1, tl0, tl1;
#pragma unroll
      for (int e = 0; e < 8; ++e) {
        unsigned short a = f2bf(vv[e]);     th0[e] = (short)a; tl0[e] = (short)f2bf(vv[e] - bf2f(a));
        unsigned short b = f2bf(vv[8 + e]); th1[e] = (short)b; tl1[e] = (short)f2bf(vv[8 + e] - bf2f(b));
      }
      const int sw = (d & 7) << 3;
      *(bf16x8*)(&VtH[(d * 64 + kb) ^ sw])     = th0;
      *(bf16x8*)(&VtH[(d * 64 + kb + 8) ^ sw]) = th1;
      *(bf16x8*)(&VtL[(d * 64 + kb) ^ sw])     = tl0;
      *(bf16x8*)(&VtL[(d * 64 + kb + 8) ^ sw]) = tl1;
    }

    // QK^T: sacc[t] = S tile (q-rows of this wave x kcols t*16..t*16+15)
    f32x4v sacc[4];
#pragma unroll
    for (int t = 0; t < 4; ++t) {
      sacc[t] = (f32x4v)(0.f);
      const int krow = t * 16 + fr;
#pragma unroll
      for (int ks = 0; ks < 2; ++ks) {
        bf16x8 kh = *(const bf16x8*)(&KsH[krow * 72 + ks * 32 + g * 8]);
        bf16x8 kl = *(const bf16x8*)(&KsL[krow * 72 + ks * 32 + g * 8]);
        sacc[t] = __builtin_amdgcn_mfma_f32_16x16x32_bf16(ql[ks], kh, sacc[t], 0, 0, 0);
        sacc[t] = __builtin_amdgcn_mfma_f32_16x16x32_bf16(qh[ks], kl, sacc[t], 0, 0, 0);
        sacc[t] = __builtin_amdgcn_mfma_f32_16x16x32_bf16(qh[ks], kh, sacc[t], 0, 0, 0);
      }
    }

    // rel-K term
    if (inband) {
#pragma unroll
      for (int r = 0; r < 4; ++r) {
        const int prow = w * 16 + g * 4 + r;
#pragma unroll
        for (int t = 0; t < 4; ++t) {
          const int dd = (k0 + t * 16 + fr) - (q0 + prow);
          const int bk = dd < -64 ? 0 : (dd > 64 ? 128 : dd + 64);
          sacc[t][r] += qr[prow * NRc + bk];
        }
      }
    } else {
      const bool neg = band < 0;
#pragma unroll
      for (int r = 0; r < 4; ++r) {
        const float qc = neg ? qr0r[r] : qr128r[r];
#pragma unroll
        for (int t = 0; t < 4; ++t) sacc[t][r] += qc;
      }
    }

    // online softmax per row r (16 lanes fr share a row)
#pragma unroll
    for (int r = 0; r < 4; ++r) {
      float tm = fmaxf(fmaxf(sacc[0][r], sacc[1][r]), fmaxf(sacc[2][r], sacc[3][r]));
      tm = fmaxf(tm, __shfl_xor(tm, 1));
      tm = fmaxf(tm, __shfl_xor(tm, 2));
      tm = fmaxf(tm, __shfl_xor(tm, 4));
      tm = fmaxf(tm, __shfl_xor(tm, 8));
      const float mn = fmaxf(m_[r], tm);
      const float f = exp2f((m_[r] - mn) * L2E);
      m_[r] = mn;
      float psum = 0.f;
#pragma unroll
      for (int t = 0; t < 4; ++t) {
        const float pv = exp2f((sacc[t][r] - mn) * L2E);
        sacc[t][r] = pv;
        psum += pv;
      }
      l_[r] = l_[r] * f + psum;
      pLo[r] *= f;
      pHi[r] *= f;
#pragma unroll
      for (int dt = 0; dt < 4; ++dt) accO[dt][r] *= f;
      const int prow = w * 16 + g * 4 + r;
      if (inband) {
#pragma unroll
        for (int t = 0; t < 4; ++t) {
          const int dd = (k0 + t * 16 + fr) - (q0 + prow);
          const float pv = sacc[t][r];
          if (dd <= -64) pLo[r] += pv;
          else if (dd >= 64) pHi[r] += pv;
          else ws[prow * NRc + dd + 64] = pv;  // single write per slot ever
        }
        if (fr == 0) mhist[(band + 1) * 64 + prow] = mn;
      } else if (band < 0) {
        pLo[r] += psum;
      } else {
        pHi[r] += psum;
      }
      // P -> bf16 hi/lo LDS (wave-private rows)
#pragma unroll
      for (int t = 0; t < 4; ++t) {
        const float pv = sacc[t][r];
        const unsigned short hb = f2bf(pv);
        PsH[prow * 72 + t * 16 + fr] = hb;
        PsL[prow * 72 + t * 16 + fr] = f2bf(pv - bf2f(hb));
      }
    }
    __syncthreads();  // barrier3: Vt ready (Ps rows are wave-private)

    // PV: accO[dt] += P @ V  (split-bf16 x3)
    bf16x8 pah[2], pal[2];
#pragma unroll
    for (int ks = 0; ks < 2; ++ks) {
      const int pidx = (w * 16 + fr) * 72 + ks * 32 + g * 8;
      pah[ks] = *(const bf16x8*)(&PsH[pidx]);
      pal[ks] = *(const bf16x8*)(&PsL[pidx]);
    }
#pragma unroll
    for (int dt = 0; dt < 4; ++dt) {
      const int d = dt * 16 + fr;
      const int sw = (d & 7) << 3;
#pragma unroll
      for (int ks = 0; ks < 2; ++ks) {
        const int vidx = (d * 64 + ks * 32 + g * 8) ^ sw;
        bf16x8 vh = *(const bf16x8*)(&VtH[vidx]);
        bf16x8 vl = *(const bf16x8*)(&VtL[vidx]);
        accO[dt] = __builtin_amdgcn_mfma_f32_16x16x32_bf16(pal[ks], vh, accO[dt], 0, 0, 0);
        accO[dt] = __builtin_amdgcn_mfma_f32_16x16x32_bf16(pah[ks], vl, accO[dt], 0, 0, 0);
        accO[dt] = __builtin_amdgcn_mfma_f32_16x16x32_bf16(pah[ks], vh, accO[dt], 0, 0, 0);
      }
    }
  }

  // ---- epilogue ----
  if (fr == 0) {
#pragma unroll
    for (int r = 0; r < 4; ++r) mfin[w * 16 + g * 4 + r] = m_[r];
  }
  __syncthreads();
  // deferred rescale: ws *= exp(m_at_write_tile - m_final)
  for (int e = tid; e < 64 * NRc; e += TPB) {
    const int row = e / NRc, b = e - row * NRc;
    const int kg = q0 + row + b - 64;
    if ((unsigned)kg < (unsigned)Sc) {
      const int lbt = (kg >> 6) - qt + 1;
      if ((unsigned)lbt < 3u)
        ws[e] *= exp2f((mhist[lbt * 64 + row] - mfin[row]) * L2E);
    }
  }
  // reduce row stats across the 16 fr lanes
#pragma unroll
  for (int r = 0; r < 4; ++r) {
    l_[r] += __shfl_xor(l_[r], 1);  l_[r] += __shfl_xor(l_[r], 2);
    l_[r] += __shfl_xor(l_[r], 4);  l_[r] += __shfl_xor(l_[r], 8);
    pLo[r] += __shfl_xor(pLo[r], 1); pLo[r] += __shfl_xor(pLo[r], 2);
    pLo[r] += __shfl_xor(pLo[r], 4); pLo[r] += __shfl_xor(pLo[r], 8);
    pHi[r] += __shfl_xor(pHi[r], 1); pHi[r] += __shfl_xor(pHi[r], 2);
    pHi[r] += __shfl_xor(pHi[r], 4); pHi[r] += __shfl_xor(pHi[r], 8);
  }
  __syncthreads();  // corrections done before tail-bucket add
  if (fr == 0) {
#pragma unroll
    for (int r = 0; r < 4; ++r) {
      const int prow = w * 16 + g * 4 + r;
      ws[prow * NRc + 0]   += pLo[r];
      ws[prow * NRc + 128] += pHi[r];
    }
  }
  // stage embV fp32 into freed Ks/Vt region
  float* eVs = (float*)smem;
  for (int e = tid; e < NRc * 16; e += TPB) {
    const int row = e >> 4, c4 = (e & 15) << 2;
    *(float4*)(eVs + row * 64 + c4) = *(const float4*)(eV + row * 64 + c4);
  }
  __syncthreads();
  // accO += ws @ embV
  for (int r = 0; r < NRc; ++r) {
    float wsv[4], ev[4];
#pragma unroll
    for (int i = 0; i < 4; ++i) wsv[i] = ws[(w * 16 + g * 4 + i) * NRc + r];
#pragma unroll
    for (int dt = 0; dt < 4; ++dt) ev[dt] = eVs[r * 64 + dt * 16 + fr];
#pragma unroll
    for (int dt = 0; dt < 4; ++dt)
#pragma unroll
      for (int i = 0; i < 4; ++i)
        accO[dt][i] += wsv[i] * ev[dt];
  }
  // normalize + store
  float* Op = O + base;
#pragma unroll
  for (int r = 0; r < 4; ++r) {
    const float inv = 1.0f / l_[r];
    const int prow = w * 16 + g * 4 + r;
#pragma unroll
    for (int dt = 0; dt < 4; ++dt)
      Op[(size_t)(q0 + prow) * Hc + dt * 16 + fr] = accO[dt][r] * inv;
  }
}

extern "C" void kernel_launch(void* const* d_in, const int* in_sizes, int n_in,
                              void* d_out, int out_size, void* d_ws, size_t ws_size,
                              hipStream_t stream) {
  const float* x    = (const float*)d_in[0];
  // d_in[1] = mask: dead in reference
  const float* Wq   = (const float*)d_in[2];
  const float* bq   = (const float*)d_in[3];
  const float* Wk   = (const float*)d_in[4];
  const float* bk   = (const float*)d_in[5];
  const float* Wv   = (const float*)d_in[6];
  const float* bv   = (const float*)d_in[7];
  const float* Wo   = (const float*)d_in[8];
  const float* bo   = (const float*)d_in[9];
  const float* embK = (const float*)d_in[10];
  const float* embV = (const float*)d_in[11];
  float* out = (float*)d_out;

  const size_t MxH = (size_t)Bc * Sc * Hc;  // 4,194,304
  float* Qb = (float*)d_ws;                 // 64MB workspace
  float* Kb = Qb + MxH;
  float* Vb = Kb + MxH;
  float* Ab = Vb + MxH;

  dim3 gg(Hc / 64, (Bc * Sc) / 128);  // (16, 32)
  gemm_mfma3<<<gg, TPB, 0, stream>>>(x, Wq, bq, Qb, Bc * Sc, Hc, Hc);
  gemm_mfma3<<<gg, TPB, 0, stream>>>(x, Wk, bk, Kb, Bc * Sc, Hc, Hc);
  gemm_mfma3<<<gg, TPB, 0, stream>>>(x, Wv, bv, Vb, Bc * Sc, Hc, Hc);

  dim3 ga(Sc / 64, Bc * NHc);  // (16, 64)
  attn_mfma<<<ga, TPB, 0, stream>>>(Qb, Kb, Vb, embK, embV, Ab);

  gemm_mfma3<<<gg, TPB, 0, stream>>>(Ab, Wo, bo, out, Bc * Sc, Hc, Hc);
}

// Round 7
// 697.780 us; speedup vs baseline: 2.8992x; 1.2178x over previous
//
#include <hip/hip_runtime.h>
#include <math.h>

// MultiHeadedAttention with relative position representations (Shaw-style).
// B=4 S=1024 H=1024 NH=16 MRP=64 VOCAB=129, fp32 in/out.
//
// Pipeline:
//   1. Q/K/V/out projections: split-bf16 ("bf16x3") MFMA GEMM.
//   2. Producer/consumer MFMA flash attention (512 thr: waves 0-3 compute,
//      waves 4-7 stage K/V global->bf16 hi/lo->swizzled LDS, double-buffered,
//      ONE barrier per k-tile). QK^T split-bf16 x3; PV = Ph*Vh + Ph*Vl.
//      rel-K via qr table; rel-V via deferred-rescale bucket table ws.
// Workspace: Q,K,V,attn_out = 4 x 16MB = 64MB fp32.

#define TPB 256
#define TPA 512
constexpr int Bc = 4, Sc = 1024, Hc = 1024, NHc = 16, DKc = 64;
constexpr int NRc = 129;               // 2*MRP+1 rel-pos buckets
constexpr float L2E = 1.44269504088896340736f;

using bf16x8 = __attribute__((ext_vector_type(8))) short;
using f32x4v = __attribute__((ext_vector_type(4))) float;

__device__ inline unsigned short f2bf(float f) {      // RNE fp32 -> bf16 bits
  unsigned int u = __float_as_uint(f);
  return (unsigned short)((u + 0x7FFFu + ((u >> 16) & 1u)) >> 16);
}
__device__ inline float bf2f(unsigned short h) {
  return __uint_as_float(((unsigned int)h) << 16);
}

// ---------------------------------------------------------------------------
// C[M][N] = A[M][K] @ W[N][K]^T + bias[N], split-bf16 MFMA (3 products).
// BM=128 BN=64 BK=32, 256 threads (4 waves, 2x2 wave grid, wave tile 64x32).
__global__ __launch_bounds__(TPB) void gemm_mfma3(
    const float* __restrict__ A, const float* __restrict__ W,
    const float* __restrict__ bias, float* __restrict__ C,
    int M, int N, int Kd) {
  __shared__ unsigned short Ah[128 * 32], Al[128 * 32];
  __shared__ unsigned short Bh[64 * 32],  Bl[64 * 32];   // 24 KB total

  const int tid = threadIdx.x;
  const int lane = tid & 63, wid = tid >> 6;
  const int wr = wid >> 1, wc = wid & 1;
  const int m0 = blockIdx.y * 128, n0 = blockIdx.x * 64;
  const int fr = lane & 15, fg = lane >> 4;

  const int ar = tid >> 1, akb = (tid & 1) * 16;
  const int br = tid >> 2, bkb = (tid & 3) * 8;
  const float* Ap = A + (size_t)(m0 + ar) * Kd + akb;
  const float* Bp = W + (size_t)(n0 + br) * Kd + bkb;

  f32x4v acc[4][2];
#pragma unroll
  for (int i = 0; i < 4; ++i)
#pragma unroll
    for (int j = 0; j < 2; ++j) acc[i][j] = (f32x4v)(0.f);

  float4 ra[4], rb[2];
#pragma unroll
  for (int q = 0; q < 4; ++q) ra[q] = *(const float4*)(Ap + q * 4);
#pragma unroll
  for (int q = 0; q < 2; ++q) rb[q] = *(const float4*)(Bp + q * 4);

  const int nK = Kd / 32;
  for (int kt = 0; kt < nK; ++kt) {
    __syncthreads();
#pragma unroll
    for (int q = 0; q < 2; ++q) {
      bf16x8 vh, vl;
#pragma unroll
      for (int e = 0; e < 8; ++e) {
        float v = ((const float*)ra)[q * 8 + e];
        unsigned short h = f2bf(v);
        vh[e] = (short)h;
        vl[e] = (short)f2bf(v - bf2f(h));
      }
      *(bf16x8*)(&Ah[ar * 32 + akb + q * 8]) = vh;
      *(bf16x8*)(&Al[ar * 32 + akb + q * 8]) = vl;
    }
    {
      bf16x8 vh, vl;
#pragma unroll
      for (int e = 0; e < 8; ++e) {
        float v = ((const float*)rb)[e];
        unsigned short h = f2bf(v);
        vh[e] = (short)h;
        vl[e] = (short)f2bf(v - bf2f(h));
      }
      *(bf16x8*)(&Bh[br * 32 + bkb]) = vh;
      *(bf16x8*)(&Bl[br * 32 + bkb]) = vl;
    }
    __syncthreads();
    if (kt + 1 < nK) {
      const float* Ap2 = Ap + (kt + 1) * 32;
      const float* Bp2 = Bp + (kt + 1) * 32;
#pragma unroll
      for (int q = 0; q < 4; ++q) ra[q] = *(const float4*)(Ap2 + q * 4);
#pragma unroll
      for (int q = 0; q < 2; ++q) rb[q] = *(const float4*)(Bp2 + q * 4);
    }
    bf16x8 fah[4], fal[4], fbh[2], fbl[2];
#pragma unroll
    for (int mf = 0; mf < 4; ++mf) {
      int r = wr * 64 + mf * 16 + fr;
      fah[mf] = *(const bf16x8*)(&Ah[r * 32 + fg * 8]);
      fal[mf] = *(const bf16x8*)(&Al[r * 32 + fg * 8]);
    }
#pragma unroll
    for (int nf = 0; nf < 2; ++nf) {
      int r = wc * 32 + nf * 16 + fr;
      fbh[nf] = *(const bf16x8*)(&Bh[r * 32 + fg * 8]);
      fbl[nf] = *(const bf16x8*)(&Bl[r * 32 + fg * 8]);
    }
#pragma unroll
    for (int mf = 0; mf < 4; ++mf)
#pragma unroll
      for (int nf = 0; nf < 2; ++nf) {
        acc[mf][nf] = __builtin_amdgcn_mfma_f32_16x16x32_bf16(
            fal[mf], fbh[nf], acc[mf][nf], 0, 0, 0);
        acc[mf][nf] = __builtin_amdgcn_mfma_f32_16x16x32_bf16(
            fah[mf], fbl[nf], acc[mf][nf], 0, 0, 0);
        acc[mf][nf] = __builtin_amdgcn_mfma_f32_16x16x32_bf16(
            fah[mf], fbh[nf], acc[mf][nf], 0, 0, 0);
      }
  }
#pragma unroll
  for (int nf = 0; nf < 2; ++nf) {
    int col = n0 + wc * 32 + nf * 16 + fr;
    float bv = bias[col];
#pragma unroll
    for (int mf = 0; mf < 4; ++mf)
#pragma unroll
      for (int rg = 0; rg < 4; ++rg) {
        int row = m0 + wr * 64 + mf * 16 + fg * 4 + rg;
        C[(size_t)row * N + col] = acc[mf][nf][rg] + bv;
      }
  }
}

// ---------------------------------------------------------------------------
// Producer staging: K rows (coalesced) + V columns (coalesced across lanes),
// fp32 -> bf16 hi/lo, slot-XOR-swizzled LDS writes (slot ^= row&7).
__device__ __forceinline__ void stage_kv(
    int k0s, int pt, const float* Kp, const float* Vp,
    unsigned short* KH, unsigned short* KL,
    unsigned short* VH, unsigned short* VL) {
  const int r = pt & 63, c = pt >> 6;      // K: row r cols c*16..; V: col d=r
  const float* ksrc = Kp + (size_t)(k0s + r) * Hc + c * 16;
  float kv[16];
#pragma unroll
  for (int q = 0; q < 4; ++q) {
    float4 t4 = *(const float4*)(ksrc + q * 4);
    kv[q * 4 + 0] = t4.x; kv[q * 4 + 1] = t4.y;
    kv[q * 4 + 2] = t4.z; kv[q * 4 + 3] = t4.w;
  }
  float vv[16];
  const float* vsrc = Vp + (size_t)(k0s + c * 16) * Hc + r;
#pragma unroll
  for (int j = 0; j < 16; ++j) vv[j] = vsrc[(size_t)j * Hc];
  bf16x8 kh[2], kl[2], vh[2], vl[2];
#pragma unroll
  for (int h2 = 0; h2 < 2; ++h2)
#pragma unroll
    for (int e = 0; e < 8; ++e) {
      const float a = kv[h2 * 8 + e];
      const unsigned short ha = f2bf(a);
      kh[h2][e] = (short)ha; kl[h2][e] = (short)f2bf(a - bf2f(ha));
      const float b = vv[h2 * 8 + e];
      const unsigned short hb = f2bf(b);
      vh[h2][e] = (short)hb; vl[h2][e] = (short)f2bf(b - bf2f(hb));
    }
  const int s0 = ((2 * c) ^ (r & 7)) * 8, s1 = ((2 * c + 1) ^ (r & 7)) * 8;
  *(bf16x8*)(KH + r * 64 + s0) = kh[0];
  *(bf16x8*)(KH + r * 64 + s1) = kh[1];
  *(bf16x8*)(KL + r * 64 + s0) = kl[0];
  *(bf16x8*)(KL + r * 64 + s1) = kl[1];
  *(bf16x8*)(VH + r * 64 + s0) = vh[0];
  *(bf16x8*)(VH + r * 64 + s1) = vh[1];
  *(bf16x8*)(VL + r * 64 + s0) = vl[0];
  *(bf16x8*)(VL + r * 64 + s1) = vl[1];
}

// ---------------------------------------------------------------------------
// Producer/consumer MFMA fused attention with relative positions.
// grid = (S/64, B*NH); block = 512 = 8 waves. Waves 0-3: compute (16 q-rows
// each); waves 4-7: stage K/V, double-buffered. One barrier per k-tile.
__global__ __launch_bounds__(TPA, 2) void attn_pc(
    const float* __restrict__ Q, const float* __restrict__ K,
    const float* __restrict__ V, const float* __restrict__ eK,
    const float* __restrict__ eV, float* __restrict__ O) {
  // LDS (bytes): KsH 0 [2][64*64]us | KsL 16384 | VtH 32768 | VtL 49152
  //  PsH 65536 [4][16*72]us | qr 74752 [64][129]f | ws 107776 [64][129]f
  //  mhist 140800 [3][64]f | mfin 141568 [64]f   total 141824
  __shared__ __align__(16) unsigned char smem[141824];
  unsigned short* KsH = (unsigned short*)(smem);
  unsigned short* KsL = (unsigned short*)(smem + 16384);
  unsigned short* VtH = (unsigned short*)(smem + 32768);
  unsigned short* VtL = (unsigned short*)(smem + 49152);
  unsigned short* PsH = (unsigned short*)(smem + 65536);
  float* qr    = (float*)(smem + 74752);
  float* ws    = (float*)(smem + 107776);
  float* mhist = (float*)(smem + 140800);
  float* mfin  = (float*)(smem + 141568);

  const int tid = threadIdx.x;
  const int lane = tid & 63, w = tid >> 6;
  const int fr = lane & 15, g = lane >> 4;
  const bool consumer = (w < 4);
  const int qt = blockIdx.x, q0 = qt << 6;
  const int bb = (int)blockIdx.y >> 4, hh = (int)blockIdx.y & 15;
  const size_t base = ((size_t)bb * Sc) * Hc + (size_t)hh * DKc;
  const float* Qp = Q + base;
  const float* Kp = K + base;
  const float* Vp = V + base;

  // ---- prologue: Q tile into ws-overlay, qr = Q . embK^T ----
  float* Qs = ws;  // [64][68] overlay, dead after qr compute
  {
    const int row = tid >> 3, c0 = (tid & 7) * 8;
    const float* src = Qp + (size_t)(q0 + row) * Hc + c0;
    *(float4*)(Qs + row * 68 + c0)     = *(const float4*)(src);
    *(float4*)(Qs + row * 68 + c0 + 4) = *(const float4*)(src + 4);
  }
  if (tid < 192) mhist[tid] = -INFINITY;
  __syncthreads();
  for (int e = tid; e < 64 * NRc; e += TPA) {
    const int row = e / NRc, rr = e - row * NRc;
    const float* qv = Qs + row * 68;
    const float* ev = eK + rr * 64;
    float a = 0.f;
#pragma unroll
    for (int c = 0; c < 16; ++c) {
      float4 x = *(const float4*)(qv + c * 4);
      float4 y = *(const float4*)(ev + c * 4);
      a += x.x * y.x + x.y * y.y + x.z * y.z + x.w * y.w;
    }
    qr[e] = a;
  }
  __syncthreads();  // qr ready; ws region reusable

  bf16x8 qh[2], ql[2];
  float qr0r[4], qr128r[4], m_[4], l_[4], pLo[4], pHi[4];
  f32x4v accO[4];
  if (consumer) {
    // Q fragments: A-frag row = fr (q-row w*16+fr), k = ks*32 + g*8 + e
#pragma unroll
    for (int ks = 0; ks < 2; ++ks) {
      const float* qsrc = Qp + (size_t)(q0 + w * 16 + fr) * Hc + ks * 32 + g * 8;
      float4 x0 = *(const float4*)(qsrc);
      float4 x1 = *(const float4*)(qsrc + 4);
      float xv[8] = {x0.x, x0.y, x0.z, x0.w, x1.x, x1.y, x1.z, x1.w};
#pragma unroll
      for (int e = 0; e < 8; ++e) {
        const unsigned short hb = f2bf(xv[e]);
        qh[ks][e] = (short)hb;
        ql[ks][e] = (short)f2bf(xv[e] - bf2f(hb));
      }
    }
#pragma unroll
    for (int r = 0; r < 4; ++r) {
      qr0r[r]   = qr[(w * 16 + g * 4 + r) * NRc + 0];
      qr128r[r] = qr[(w * 16 + g * 4 + r) * NRc + 128];
      m_[r] = -INFINITY; l_[r] = 0.f; pLo[r] = 0.f; pHi[r] = 0.f;
    }
#pragma unroll
    for (int dt = 0; dt < 4; ++dt) accO[dt] = (f32x4v)(0.f);
    for (int e = tid; e < 64 * NRc; e += TPB) ws[e] = 0.0f;  // 256 consumers
  } else {
    stage_kv(0, tid - 256, Kp, Vp, KsH, KsL, VtH, VtL);      // tile 0 -> buf 0
  }
  __syncthreads();  // buf0 staged, ws zeroed

  // ---- main loop: one barrier per tile ----
  for (int kt = 0; kt < Sc / 64; ++kt) {
    const int k0 = kt << 6;
    const int band = kt - qt;
    const bool inband = (band >= -1) && (band <= 1);
    const int buf = kt & 1;
    if (consumer) {
      const unsigned short* KH = KsH + buf * 4096;
      const unsigned short* KL = KsL + buf * 4096;
      const unsigned short* VH = VtH + buf * 4096;
      const unsigned short* VL = VtL + buf * 4096;
      // QK^T (split-bf16 x3): sacc[t][r] = S[q=w*16+g*4+r][k=k0+t*16+fr]
      f32x4v sacc[4];
      __builtin_amdgcn_s_setprio(1);
#pragma unroll
      for (int t = 0; t < 4; ++t) {
        sacc[t] = (f32x4v)(0.f);
        const int kr = t * 16 + fr;
#pragma unroll
        for (int ks = 0; ks < 2; ++ks) {
          const int off = kr * 64 + (((ks * 4 + g) ^ (fr & 7)) * 8);
          bf16x8 kh = *(const bf16x8*)(KH + off);
          bf16x8 kl = *(const bf16x8*)(KL + off);
          sacc[t] = __builtin_amdgcn_mfma_f32_16x16x32_bf16(ql[ks], kh, sacc[t], 0, 0, 0);
          sacc[t] = __builtin_amdgcn_mfma_f32_16x16x32_bf16(qh[ks], kl, sacc[t], 0, 0, 0);
          sacc[t] = __builtin_amdgcn_mfma_f32_16x16x32_bf16(qh[ks], kh, sacc[t], 0, 0, 0);
        }
      }
      __builtin_amdgcn_s_setprio(0);
      // rel-K
      if (inband) {
#pragma unroll
        for (int r = 0; r < 4; ++r) {
          const int prow = w * 16 + g * 4 + r;
#pragma unroll
          for (int t = 0; t < 4; ++t) {
            const int dd = (k0 + t * 16 + fr) - (q0 + prow);
            const int bk = dd < -64 ? 0 : (dd > 64 ? 128 : dd + 64);
            sacc[t][r] += qr[prow * NRc + bk];
          }
        }
      } else {
        const bool neg = band < 0;
#pragma unroll
        for (int r = 0; r < 4; ++r) {
          const float qc = neg ? qr0r[r] : qr128r[r];
#pragma unroll
          for (int t = 0; t < 4; ++t) sacc[t][r] += qc;
        }
      }
      // online softmax (rows shared by the 16 fr-lanes)
#pragma unroll
      for (int r = 0; r < 4; ++r) {
        float tm = fmaxf(fmaxf(sacc[0][r], sacc[1][r]), fmaxf(sacc[2][r], sacc[3][r]));
        tm = fmaxf(tm, __shfl_xor(tm, 1));
        tm = fmaxf(tm, __shfl_xor(tm, 2));
        tm = fmaxf(tm, __shfl_xor(tm, 4));
        tm = fmaxf(tm, __shfl_xor(tm, 8));
        const float mn = fmaxf(m_[r], tm);
        const float f = exp2f((m_[r] - mn) * L2E);
        m_[r] = mn;
        float p[4], psum = 0.f;
#pragma unroll
        for (int t = 0; t < 4; ++t) {
          p[t] = exp2f((sacc[t][r] - mn) * L2E);
          psum += p[t];
        }
        l_[r] = l_[r] * f + psum;
        pLo[r] *= f;
        pHi[r] *= f;
#pragma unroll
        for (int dt = 0; dt < 4; ++dt) accO[dt][r] *= f;
        const int prow = w * 16 + g * 4 + r;
        if (inband) {
#pragma unroll
          for (int t = 0; t < 4; ++t) {
            const int dd = (k0 + t * 16 + fr) - (q0 + prow);
            if (dd <= -64) pLo[r] += p[t];
            else if (dd >= 64) pHi[r] += p[t];
            else ws[prow * NRc + dd + 64] = p[t];  // single write per slot
          }
          if (fr == 0) mhist[(band + 1) * 64 + prow] = mn;
        } else if (band < 0) {
          pLo[r] += psum;
        } else {
          pHi[r] += psum;
        }
        // P (bf16 hi only) -> wave-private Ps rows
#pragma unroll
        for (int t = 0; t < 4; ++t)
          PsH[w * 1152 + (g * 4 + r) * 72 + t * 16 + fr] = f2bf(p[t]);
      }
      // intra-wave LDS RAW fence (no block barrier needed: rows wave-private)
      asm volatile("s_waitcnt lgkmcnt(0)" ::: "memory");
      __builtin_amdgcn_sched_barrier(0);
      // PV: accO += Ph @ (Vh + Vl)
      bf16x8 pah[2];
#pragma unroll
      for (int ks = 0; ks < 2; ++ks)
        pah[ks] = *(const bf16x8*)(PsH + w * 1152 + fr * 72 + ks * 32 + g * 8);
      __builtin_amdgcn_s_setprio(1);
#pragma unroll
      for (int dt = 0; dt < 4; ++dt) {
        const int vr = dt * 16 + fr;
#pragma unroll
        for (int ks = 0; ks < 2; ++ks) {
          const int off = vr * 64 + (((ks * 4 + g) ^ (fr & 7)) * 8);
          bf16x8 vh = *(const bf16x8*)(VH + off);
          bf16x8 vl = *(const bf16x8*)(VL + off);
          accO[dt] = __builtin_amdgcn_mfma_f32_16x16x32_bf16(pah[ks], vh, accO[dt], 0, 0, 0);
          accO[dt] = __builtin_amdgcn_mfma_f32_16x16x32_bf16(pah[ks], vl, accO[dt], 0, 0, 0);
        }
      }
      __builtin_amdgcn_s_setprio(0);
    } else {
      if (kt + 1 < Sc / 64) {
        const int nb = (kt + 1) & 1;
        stage_kv((kt + 1) << 6, tid - 256, Kp, Vp,
                 KsH + nb * 4096, KsL + nb * 4096,
                 VtH + nb * 4096, VtL + nb * 4096);
      }
    }
    __syncthreads();  // tile boundary: buf consumed / buf^1 staged
  }

  // ---- epilogue ----
  if (consumer) {
    if (fr == 0) {
#pragma unroll
      for (int r = 0; r < 4; ++r) mfin[w * 16 + g * 4 + r] = m_[r];
    }
#pragma unroll
    for (int r = 0; r < 4; ++r) {
      l_[r] += __shfl_xor(l_[r], 1);  l_[r] += __shfl_xor(l_[r], 2);
      l_[r] += __shfl_xor(l_[r], 4);  l_[r] += __shfl_xor(l_[r], 8);
      pLo[r] += __shfl_xor(pLo[r], 1); pLo[r] += __shfl_xor(pLo[r], 2);
      pLo[r] += __shfl_xor(pLo[r], 4); pLo[r] += __shfl_xor(pLo[r], 8);
      pHi[r] += __shfl_xor(pHi[r], 1); pHi[r] += __shfl_xor(pHi[r], 2);
      pHi[r] += __shfl_xor(pHi[r], 4); pHi[r] += __shfl_xor(pHi[r], 8);
    }
  }
  __syncthreads();  // mfin/mhist visible
  // deferred rescale: ws *= exp(m_at_write_tile - m_final)
  for (int e = tid; e < 64 * NRc; e += TPA) {
    const int row = e / NRc, b = e - row * NRc;
    const int kg = q0 + row + b - 64;
    if ((unsigned)kg < (unsigned)Sc) {
      const int lbt = (kg >> 6) - qt + 1;
      if ((unsigned)lbt < 3u)
        ws[e] *= exp2f((mhist[lbt * 64 + row] - mfin[row]) * L2E);
    }
  }
  __syncthreads();  // rescale done before tail add
  if (consumer && fr == 0) {
#pragma unroll
    for (int r = 0; r < 4; ++r) {
      const int prow = w * 16 + g * 4 + r;
      ws[prow * NRc + 0]   += pLo[r];
      ws[prow * NRc + 128] += pHi[r];
    }
  }
  // stage embV fp32 into freed Ks/Vt region
  float* eVs = (float*)smem;
  for (int e = tid; e < NRc * 16; e += TPA) {
    const int row = e >> 4, c4 = (e & 15) << 2;
    *(float4*)(eVs + row * 64 + c4) = *(const float4*)(eV + row * 64 + c4);
  }
  __syncthreads();
  if (consumer) {
    // accO += ws @ embV
    for (int r = 0; r < NRc; ++r) {
      float wsv[4], ev[4];
#pragma unroll
      for (int i = 0; i < 4; ++i) wsv[i] = ws[(w * 16 + g * 4 + i) * NRc + r];
#pragma unroll
      for (int dt = 0; dt < 4; ++dt) ev[dt] = eVs[r * 64 + dt * 16 + fr];
#pragma unroll
      for (int dt = 0; dt < 4; ++dt)
#pragma unroll
        for (int i = 0; i < 4; ++i)
          accO[dt][i] += wsv[i] * ev[dt];
    }
    // normalize + store
    float* Op = O + base;
#pragma unroll
    for (int r = 0; r < 4; ++r) {
      const float inv = 1.0f / l_[r];
      const int prow = w * 16 + g * 4 + r;
#pragma unroll
      for (int dt = 0; dt < 4; ++dt)
        Op[(size_t)(q0 + prow) * Hc + dt * 16 + fr] = accO[dt][r] * inv;
    }
  }
}

extern "C" void kernel_launch(void* const* d_in, const int* in_sizes, int n_in,
                              void* d_out, int out_size, void* d_ws, size_t ws_size,
                              hipStream_t stream) {
  const float* x    = (const float*)d_in[0];
  // d_in[1] = mask: dead in reference
  const float* Wq   = (const float*)d_in[2];
  const float* bq   = (const float*)d_in[3];
  const float* Wk   = (const float*)d_in[4];
  const float* bk   = (const float*)d_in[5];
  const float* Wv   = (const float*)d_in[6];
  const float* bv   = (const float*)d_in[7];
  const float* Wo   = (const float*)d_in[8];
  const float* bo   = (const float*)d_in[9];
  const float* embK = (const float*)d_in[10];
  const float* embV = (const float*)d_in[11];
  float* out = (float*)d_out;

  const size_t MxH = (size_t)Bc * Sc * Hc;  // 4,194,304
  float* Qb = (float*)d_ws;                 // 64MB workspace
  float* Kb = Qb + MxH;
  float* Vb = Kb + MxH;
  float* Ab = Vb + MxH;

  dim3 gg(Hc / 64, (Bc * Sc) / 128);  // (16, 32)
  gemm_mfma3<<<gg, TPB, 0, stream>>>(x, Wq, bq, Qb, Bc * Sc, Hc, Hc);
  gemm_mfma3<<<gg, TPB, 0, stream>>>(x, Wk, bk, Kb, Bc * Sc, Hc, Hc);
  gemm_mfma3<<<gg, TPB, 0, stream>>>(x, Wv, bv, Vb, Bc * Sc, Hc, Hc);

  dim3 ga(Sc / 64, Bc * NHc);  // (16, 64)
  attn_pc<<<ga, TPA, 0, stream>>>(Qb, Kb, Vb, embK, embV, Ab);

  dim3 go(Hc / 64, (Bc * Sc) / 128);
  gemm_mfma3<<<go, TPB, 0, stream>>>(Ab, Wo, bo, out, Bc * Sc, Hc, Hc);
}

// Round 9
// 672.739 us; speedup vs baseline: 3.0071x; 1.0372x over previous
//
#include <hip/hip_runtime.h>
#include <hip/hip_bf16.h>
#include <math.h>

// MultiHeadedAttention with relative position representations (Shaw-style).
// B=4 S=1024 H=1024 NH=16 MRP=64 VOCAB=129, fp32 in/out.
//
// Pipeline:
//   1. Projections (split-bf16 x3 MFMA GEMM). K GEMM emits bf16 hi/lo
//      row-major; V GEMM emits bf16 hi/lo TRANSPOSED per head [bb,hh,d,s]
//      (conversion done once here, not 16x per k-tile in attention).
//   2. Producer/consumer MFMA flash attention (512 thr: waves 0-3 compute,
//      waves 4-7 copy pre-converted bf16 K/V global->LDS with line-clean,
//      pre-swizzled-source addressing; double-buffered; ONE barrier/tile).
//      QK^T split-bf16 x3; PV = Ph*(Vh+Vl). rel-K via qr table; rel-V via
//      deferred-rescale bucket table ws.
// Workspace: Qf32 16 + Khi 8 + Klo 8 + Vthi 8 + Vtlo 8 + Ab 16 = 64MB.

#define TPB 256
#define TPA 512
constexpr int Bc = 4, Sc = 1024, Hc = 1024, NHc = 16, DKc = 64;
constexpr int NRc = 129;               // 2*MRP+1 rel-pos buckets
constexpr float L2E = 1.44269504088896340736f;

using bf16x8 = __attribute__((ext_vector_type(8))) short;
using f32x4v = __attribute__((ext_vector_type(4))) float;

__device__ inline unsigned short f2bf(float f) {      // RNE via HW cvt
  __hip_bfloat16 h = __float2bfloat16(f);
  return *reinterpret_cast<unsigned short*>(&h);
}
__device__ inline float bf2f(unsigned short h) {
  return __uint_as_float(((unsigned int)h) << 16);
}

// ---------------------------------------------------------------------------
// C = A @ W^T + bias, split-bf16 MFMA (3 products). BM=128 BN=64 BK=32,
// 256 threads (4 waves, 2x2 wave grid, wave tile 64x32).
// MODE 0: fp32 C.  MODE 1: bf16 hi/lo row-major (K).  MODE 2: bf16 hi/lo
// transposed per-head [ (bb*16+hh)*64+d ][ s ] (V^T).
template <int MODE>
__global__ __launch_bounds__(TPB) void gemm_mfma3(
    const float* __restrict__ A, const float* __restrict__ W,
    const float* __restrict__ bias, float* __restrict__ C,
    unsigned short* __restrict__ CH, unsigned short* __restrict__ CL,
    int M, int N, int Kd) {
  __shared__ unsigned short Ah[128 * 32], Al[128 * 32];
  __shared__ unsigned short Bh[64 * 32],  Bl[64 * 32];   // 24 KB total

  const int tid = threadIdx.x;
  const int lane = tid & 63, wid = tid >> 6;
  const int wr = wid >> 1, wc = wid & 1;
  const int m0 = blockIdx.y * 128, n0 = blockIdx.x * 64;
  const int fr = lane & 15, fg = lane >> 4;

  const int ar = tid >> 1, akb = (tid & 1) * 16;
  const int br = tid >> 2, bkb = (tid & 3) * 8;
  const float* Ap = A + (size_t)(m0 + ar) * Kd + akb;
  const float* Bp = W + (size_t)(n0 + br) * Kd + bkb;

  f32x4v acc[4][2];
#pragma unroll
  for (int i = 0; i < 4; ++i)
#pragma unroll
    for (int j = 0; j < 2; ++j) acc[i][j] = (f32x4v)(0.f);

  float4 ra[4], rb[2];
#pragma unroll
  for (int q = 0; q < 4; ++q) ra[q] = *(const float4*)(Ap + q * 4);
#pragma unroll
  for (int q = 0; q < 2; ++q) rb[q] = *(const float4*)(Bp + q * 4);

  const int nK = Kd / 32;
  for (int kt = 0; kt < nK; ++kt) {
    __syncthreads();
#pragma unroll
    for (int q = 0; q < 2; ++q) {
      bf16x8 vh, vl;
#pragma unroll
      for (int e = 0; e < 8; ++e) {
        float v = ((const float*)ra)[q * 8 + e];
        unsigned short h = f2bf(v);
        vh[e] = (short)h;
        vl[e] = (short)f2bf(v - bf2f(h));
      }
      *(bf16x8*)(&Ah[ar * 32 + akb + q * 8]) = vh;
      *(bf16x8*)(&Al[ar * 32 + akb + q * 8]) = vl;
    }
    {
      bf16x8 vh, vl;
#pragma unroll
      for (int e = 0; e < 8; ++e) {
        float v = ((const float*)rb)[e];
        unsigned short h = f2bf(v);
        vh[e] = (short)h;
        vl[e] = (short)f2bf(v - bf2f(h));
      }
      *(bf16x8*)(&Bh[br * 32 + bkb]) = vh;
      *(bf16x8*)(&Bl[br * 32 + bkb]) = vl;
    }
    __syncthreads();
    if (kt + 1 < nK) {
      const float* Ap2 = Ap + (kt + 1) * 32;
      const float* Bp2 = Bp + (kt + 1) * 32;
#pragma unroll
      for (int q = 0; q < 4; ++q) ra[q] = *(const float4*)(Ap2 + q * 4);
#pragma unroll
      for (int q = 0; q < 2; ++q) rb[q] = *(const float4*)(Bp2 + q * 4);
    }
    bf16x8 fah[4], fal[4], fbh[2], fbl[2];
#pragma unroll
    for (int mf = 0; mf < 4; ++mf) {
      int r = wr * 64 + mf * 16 + fr;
      fah[mf] = *(const bf16x8*)(&Ah[r * 32 + fg * 8]);
      fal[mf] = *(const bf16x8*)(&Al[r * 32 + fg * 8]);
    }
#pragma unroll
    for (int nf = 0; nf < 2; ++nf) {
      int r = wc * 32 + nf * 16 + fr;
      fbh[nf] = *(const bf16x8*)(&Bh[r * 32 + fg * 8]);
      fbl[nf] = *(const bf16x8*)(&Bl[r * 32 + fg * 8]);
    }
#pragma unroll
    for (int mf = 0; mf < 4; ++mf)
#pragma unroll
      for (int nf = 0; nf < 2; ++nf) {
        acc[mf][nf] = __builtin_amdgcn_mfma_f32_16x16x32_bf16(
            fal[mf], fbh[nf], acc[mf][nf], 0, 0, 0);
        acc[mf][nf] = __builtin_amdgcn_mfma_f32_16x16x32_bf16(
            fah[mf], fbl[nf], acc[mf][nf], 0, 0, 0);
        acc[mf][nf] = __builtin_amdgcn_mfma_f32_16x16x32_bf16(
            fah[mf], fbh[nf], acc[mf][nf], 0, 0, 0);
      }
  }
  // epilogue (D row=(lane>>4)*4+reg, col=lane&15)
#pragma unroll
  for (int nf = 0; nf < 2; ++nf) {
    const int col = n0 + wc * 32 + nf * 16 + fr;
    const float bv = bias[col];
#pragma unroll
    for (int mf = 0; mf < 4; ++mf) {
      const int row0 = m0 + wr * 64 + mf * 16 + fg * 4;
      if (MODE == 0) {
#pragma unroll
        for (int rg = 0; rg < 4; ++rg)
          C[(size_t)(row0 + rg) * N + col] = acc[mf][nf][rg] + bv;
      } else if (MODE == 1) {
#pragma unroll
        for (int rg = 0; rg < 4; ++rg) {
          const float v = acc[mf][nf][rg] + bv;
          const unsigned short h = f2bf(v);
          CH[(size_t)(row0 + rg) * N + col] = h;
          CL[(size_t)(row0 + rg) * N + col] = f2bf(v - bf2f(h));
        }
      } else {
        // V^T: s = row0+rg consecutive -> pack 4 bf16 per b64 store
        const int bb2 = row0 >> 10, s0 = row0 & 1023;
        const int hh2 = col >> 6, d = col & 63;
        const size_t basei =
            (((size_t)bb2 * NHc + hh2) * DKc + d) * (size_t)Sc + s0;
        unsigned short hs[4], ls[4];
#pragma unroll
        for (int rg = 0; rg < 4; ++rg) {
          const float v = acc[mf][nf][rg] + bv;
          hs[rg] = f2bf(v);
          ls[rg] = f2bf(v - bf2f(hs[rg]));
        }
        uint2 ph, pl;
        ph.x = (unsigned)hs[0] | ((unsigned)hs[1] << 16);
        ph.y = (unsigned)hs[2] | ((unsigned)hs[3] << 16);
        pl.x = (unsigned)ls[0] | ((unsigned)ls[1] << 16);
        pl.y = (unsigned)ls[2] | ((unsigned)ls[3] << 16);
        *(uint2*)(CH + basei) = ph;
        *(uint2*)(CL + basei) = pl;
      }
    }
  }
}

// ---------------------------------------------------------------------------
// Producer staging: copy one 64x64-bf16 tile (8KB) global->LDS.
// Lane l, instr i: global granule (row=i*8+(l>>3), gcol=(l&7)^(row&7))
// -> linear LDS granule i*64+l. Loads cover full 128B rows (line-clean);
// LDS writes linear b128 (conflict-free). Consumer's swizzled read
// (slot = gcol ^ (row&7)) sees the same involution as before.
__device__ __forceinline__ void stage8(const unsigned short* __restrict__ g,
                                       int lane, unsigned short* ldsT,
                                       size_t koff) {
  float4 t[8];
#pragma unroll
  for (int i = 0; i < 8; ++i) {
    const int row = i * 8 + (lane >> 3);
    const int gcol = (lane & 7) ^ (row & 7);
    t[i] = *(const float4*)(g + koff + (size_t)row * 1024 + gcol * 8);
  }
#pragma unroll
  for (int i = 0; i < 8; ++i)
    *(float4*)(ldsT + (size_t)(i * 64 + lane) * 8) = t[i];
}

// ---------------------------------------------------------------------------
// Producer/consumer MFMA fused attention with relative positions.
// grid = (S/64, B*NH); block = 512 = 8 waves. Waves 0-3: compute (16 q-rows
// each); waves 4-7: copy K/V (one tensor each), double-buffered.
__global__ __launch_bounds__(TPA, 2) void attn_pc(
    const float* __restrict__ Q,
    const unsigned short* __restrict__ KHg, const unsigned short* __restrict__ KLg,
    const unsigned short* __restrict__ VHg, const unsigned short* __restrict__ VLg,
    const float* __restrict__ eK, const float* __restrict__ eV,
    float* __restrict__ O) {
  // LDS (bytes): KsH 0 [2][4096]us | KsL 16384 | VtH 32768 | VtL 49152
  //  PsH 65536 [4][16*72]us | qr 74752 [64][129]f | ws 107776 [64][129]f
  //  mhist 140800 [3][64]f | mfin 141568 [64]f   total 141824
  __shared__ __align__(16) unsigned char smem[141824];
  unsigned short* KsH = (unsigned short*)(smem);
  unsigned short* KsL = (unsigned short*)(smem + 16384);
  unsigned short* VtH = (unsigned short*)(smem + 32768);
  unsigned short* VtL = (unsigned short*)(smem + 49152);
  unsigned short* PsH = (unsigned short*)(smem + 65536);
  float* qr    = (float*)(smem + 74752);
  float* ws    = (float*)(smem + 107776);
  float* mhist = (float*)(smem + 140800);
  float* mfin  = (float*)(smem + 141568);

  const int tid = threadIdx.x;
  const int lane = tid & 63, w = tid >> 6;
  const int fr = lane & 15, g = lane >> 4;
  const bool consumer = (w < 4);
  const int qt = blockIdx.x, q0 = qt << 6;
  const int bb = (int)blockIdx.y >> 4, hh = (int)blockIdx.y & 15;
  const size_t base = ((size_t)bb * Sc) * Hc + (size_t)hh * DKc;
  const float* Qp = Q + base;

  // ---- prologue: Q tile into ws-overlay, qr = Q . embK^T ----
  float* Qs = ws;  // [64][68] overlay, dead after qr compute
  {
    const int row = tid >> 3, c0 = (tid & 7) * 8;
    const float* src = Qp + (size_t)(q0 + row) * Hc + c0;
    *(float4*)(Qs + row * 68 + c0)     = *(const float4*)(src);
    *(float4*)(Qs + row * 68 + c0 + 4) = *(const float4*)(src + 4);
  }
  if (tid < 192) mhist[tid] = -INFINITY;
  __syncthreads();
  for (int e = tid; e < 64 * NRc; e += TPA) {
    const int row = e / NRc, rr = e - row * NRc;
    const float* qv = Qs + row * 68;
    const float* ev = eK + rr * 64;
    float a = 0.f;
#pragma unroll
    for (int c = 0; c < 16; ++c) {
      float4 x = *(const float4*)(qv + c * 4);
      float4 y = *(const float4*)(ev + c * 4);
      a += x.x * y.x + x.y * y.y + x.z * y.z + x.w * y.w;
    }
    qr[e] = a;
  }
  __syncthreads();  // qr ready; ws region reusable

  bf16x8 qh[2], ql[2];
  float qr0r[4], qr128r[4], m_[4], l_[4], pLo[4], pHi[4];
  f32x4v accO[4];
  const unsigned short* gsrcT = nullptr;
  unsigned short* ldsT = nullptr;
  size_t kmul = 0;
  if (consumer) {
    // Q fragments: A-frag row = fr (q-row w*16+fr), k = ks*32 + g*8 + e
#pragma unroll
    for (int ks = 0; ks < 2; ++ks) {
      const float* qsrc = Qp + (size_t)(q0 + w * 16 + fr) * Hc + ks * 32 + g * 8;
      float4 x0 = *(const float4*)(qsrc);
      float4 x1 = *(const float4*)(qsrc + 4);
      float xv[8] = {x0.x, x0.y, x0.z, x0.w, x1.x, x1.y, x1.z, x1.w};
#pragma unroll
      for (int e = 0; e < 8; ++e) {
        const unsigned short hb = f2bf(xv[e]);
        qh[ks][e] = (short)hb;
        ql[ks][e] = (short)f2bf(xv[e] - bf2f(hb));
      }
    }
#pragma unroll
    for (int r = 0; r < 4; ++r) {
      qr0r[r]   = qr[(w * 16 + g * 4 + r) * NRc + 0];
      qr128r[r] = qr[(w * 16 + g * 4 + r) * NRc + 128];
      m_[r] = -INFINITY; l_[r] = 0.f; pLo[r] = 0.f; pHi[r] = 0.f;
    }
#pragma unroll
    for (int dt = 0; dt < 4; ++dt) accO[dt] = (f32x4v)(0.f);
    for (int e = tid; e < 64 * NRc; e += TPB) ws[e] = 0.0f;  // 256 consumers
  } else {
    const int wp = w - 4;
    const size_t kb = (size_t)bb * Sc * Hc + (size_t)hh * DKc;  // K[s0][h0]
    const size_t vb = ((size_t)(bb * NHc + hh)) * DKc * Sc;     // Vt[d0][0]
    if (wp == 0)      { gsrcT = KHg + kb; ldsT = KsH; kmul = 1024; }
    else if (wp == 1) { gsrcT = KLg + kb; ldsT = KsL; kmul = 1024; }
    else if (wp == 2) { gsrcT = VHg + vb; ldsT = VtH; kmul = 1; }
    else              { gsrcT = VLg + vb; ldsT = VtL; kmul = 1; }
    stage8(gsrcT, lane, ldsT, 0);                // tile 0 -> buf 0
  }
  __syncthreads();  // buf0 staged, ws zeroed

  // ---- main loop: one barrier per tile ----
  for (int kt = 0; kt < Sc / 64; ++kt) {
    const int k0 = kt << 6;
    const int band = kt - qt;
    const bool inband = (band >= -1) && (band <= 1);
    const int buf = kt & 1;
    if (consumer) {
      const unsigned short* KH = KsH + buf * 4096;
      const unsigned short* KL = KsL + buf * 4096;
      const unsigned short* VH = VtH + buf * 4096;
      const unsigned short* VL = VtL + buf * 4096;
      // QK^T (split-bf16 x3): sacc[t][r] = S[q=w*16+g*4+r][k=k0+t*16+fr]
      f32x4v sacc[4];
      __builtin_amdgcn_s_setprio(1);
#pragma unroll
      for (int t = 0; t < 4; ++t) {
        sacc[t] = (f32x4v)(0.f);
        const int kr = t * 16 + fr;
#pragma unroll
        for (int ks = 0; ks < 2; ++ks) {
          const int off = kr * 64 + (((ks * 4 + g) ^ (fr & 7)) * 8);
          bf16x8 kh = *(const bf16x8*)(KH + off);
          bf16x8 kl = *(const bf16x8*)(KL + off);
          sacc[t] = __builtin_amdgcn_mfma_f32_16x16x32_bf16(ql[ks], kh, sacc[t], 0, 0, 0);
          sacc[t] = __builtin_amdgcn_mfma_f32_16x16x32_bf16(qh[ks], kl, sacc[t], 0, 0, 0);
          sacc[t] = __builtin_amdgcn_mfma_f32_16x16x32_bf16(qh[ks], kh, sacc[t], 0, 0, 0);
        }
      }
      __builtin_amdgcn_s_setprio(0);
      // rel-K
      if (inband) {
#pragma unroll
        for (int r = 0; r < 4; ++r) {
          const int prow = w * 16 + g * 4 + r;
#pragma unroll
          for (int t = 0; t < 4; ++t) {
            const int dd = (k0 + t * 16 + fr) - (q0 + prow);
            const int bk = dd < -64 ? 0 : (dd > 64 ? 128 : dd + 64);
            sacc[t][r] += qr[prow * NRc + bk];
          }
        }
      } else {
        const bool neg = band < 0;
#pragma unroll
        for (int r = 0; r < 4; ++r) {
          const float qc = neg ? qr0r[r] : qr128r[r];
#pragma unroll
          for (int t = 0; t < 4; ++t) sacc[t][r] += qc;
        }
      }
      // online softmax (rows shared by the 16 fr-lanes)
#pragma unroll
      for (int r = 0; r < 4; ++r) {
        float tm = fmaxf(fmaxf(sacc[0][r], sacc[1][r]), fmaxf(sacc[2][r], sacc[3][r]));
        tm = fmaxf(tm, __shfl_xor(tm, 1));
        tm = fmaxf(tm, __shfl_xor(tm, 2));
        tm = fmaxf(tm, __shfl_xor(tm, 4));
        tm = fmaxf(tm, __shfl_xor(tm, 8));
        const float mn = fmaxf(m_[r], tm);
        const float f = exp2f((m_[r] - mn) * L2E);
        m_[r] = mn;
        float p[4], psum = 0.f;
#pragma unroll
        for (int t = 0; t < 4; ++t) {
          p[t] = exp2f((sacc[t][r] - mn) * L2E);
          psum += p[t];
        }
        l_[r] = l_[r] * f + psum;
        pLo[r] *= f;
        pHi[r] *= f;
#pragma unroll
        for (int dt = 0; dt < 4; ++dt) accO[dt][r] *= f;
        const int prow = w * 16 + g * 4 + r;
        if (inband) {
#pragma unroll
          for (int t = 0; t < 4; ++t) {
            const int dd = (k0 + t * 16 + fr) - (q0 + prow);
            if (dd <= -64) pLo[r] += p[t];
            else if (dd >= 64) pHi[r] += p[t];
            else ws[prow * NRc + dd + 64] = p[t];  // single write per slot
          }
          if (fr == 0) mhist[(band + 1) * 64 + prow] = mn;
        } else if (band < 0) {
          pLo[r] += psum;
        } else {
          pHi[r] += psum;
        }
        // P (bf16 hi only) -> wave-private Ps rows
#pragma unroll
        for (int t = 0; t < 4; ++t)
          PsH[w * 1152 + (g * 4 + r) * 72 + t * 16 + fr] = f2bf(p[t]);
      }
      // intra-wave LDS RAW fence (rows wave-private; no block barrier needed)
      asm volatile("s_waitcnt lgkmcnt(0)" ::: "memory");
      __builtin_amdgcn_sched_barrier(0);
      // PV: accO += Ph @ (Vh + Vl)
      bf16x8 pah[2];
#pragma unroll
      for (int ks = 0; ks < 2; ++ks)
        pah[ks] = *(const bf16x8*)(PsH + w * 1152 + fr * 72 + ks * 32 + g * 8);
      __builtin_amdgcn_s_setprio(1);
#pragma unroll
      for (int dt = 0; dt < 4; ++dt) {
        const int vr = dt * 16 + fr;
#pragma unroll
        for (int ks = 0; ks < 2; ++ks) {
          const int off = vr * 64 + (((ks * 4 + g) ^ (fr & 7)) * 8);
          bf16x8 vh = *(const bf16x8*)(VH + off);
          bf16x8 vl = *(const bf16x8*)(VL + off);
          accO[dt] = __builtin_amdgcn_mfma_f32_16x16x32_bf16(pah[ks], vh, accO[dt], 0, 0, 0);
          accO[dt] = __builtin_amdgcn_mfma_f32_16x16x32_bf16(pah[ks], vl, accO[dt], 0, 0, 0);
        }
      }
      __builtin_amdgcn_s_setprio(0);
    } else {
      if (kt + 1 < Sc / 64) {
        const int nb = (kt + 1) & 1;
        stage8(gsrcT, lane, ldsT + nb * 4096, (size_t)(kt + 1) * 64 * kmul);
      }
    }
    __syncthreads();  // tile boundary: buf consumed / buf^1 staged
  }

  // ---- epilogue ----
  if (consumer) {
    if (fr == 0) {
#pragma unroll
      for (int r = 0; r < 4; ++r) mfin[w * 16 + g * 4 + r] = m_[r];
    }
#pragma unroll
    for (int r = 0; r < 4; ++r) {
      l_[r] += __shfl_xor(l_[r], 1);  l_[r] += __shfl_xor(l_[r], 2);
      l_[r] += __shfl_xor(l_[r], 4);  l_[r] += __shfl_xor(l_[r], 8);
      pLo[r] += __shfl_xor(pLo[r], 1); pLo[r] += __shfl_xor(pLo[r], 2);
      pLo[r] += __shfl_xor(pLo[r], 4); pLo[r] += __shfl_xor(pLo[r], 8);
      pHi[r] += __shfl_xor(pHi[r], 1); pHi[r] += __shfl_xor(pHi[r], 2);
      pHi[r] += __shfl_xor(pHi[r], 4); pHi[r] += __shfl_xor(pHi[r], 8);
    }
  }
  __syncthreads();  // mfin/mhist visible
  // deferred rescale: ws *= exp(m_at_write_tile - m_final)
  for (int e = tid; e < 64 * NRc; e += TPA) {
    const int row = e / NRc, b = e - row * NRc;
    const int kg = q0 + row + b - 64;
    if ((unsigned)kg < (unsigned)Sc) {
      const int lbt = (kg >> 6) - qt + 1;
      if ((unsigned)lbt < 3u)
        ws[e] *= exp2f((mhist[lbt * 64 + row] - mfin[row]) * L2E);
    }
  }
  __syncthreads();  // rescale done before tail add
  if (consumer && fr == 0) {
#pragma unroll
    for (int r = 0; r < 4; ++r) {
      const int prow = w * 16 + g * 4 + r;
      ws[prow * NRc + 0]   += pLo[r];
      ws[prow * NRc + 128] += pHi[r];
    }
  }
  // stage embV fp32 into freed Ks/Vt region
  float* eVs = (float*)smem;
  for (int e = tid; e < NRc * 16; e += TPA) {
    const int row = e >> 4, c4 = (e & 15) << 2;
    *(float4*)(eVs + row * 64 + c4) = *(const float4*)(eV + row * 64 + c4);
  }
  __syncthreads();
  if (consumer) {
    // accO += ws @ embV
    for (int r = 0; r < NRc; ++r) {
      float wsv[4], ev[4];
#pragma unroll
      for (int i = 0; i < 4; ++i) wsv[i] = ws[(w * 16 + g * 4 + i) * NRc + r];
#pragma unroll
      for (int dt = 0; dt < 4; ++dt) ev[dt] = eVs[r * 64 + dt * 16 + fr];
#pragma unroll
      for (int dt = 0; dt < 4; ++dt)
#pragma unroll
        for (int i = 0; i < 4; ++i)
          accO[dt][i] += wsv[i] * ev[dt];
    }
    // normalize + store
    float* Op = O + base;
#pragma unroll
    for (int r = 0; r < 4; ++r) {
      const float inv = 1.0f / l_[r];
      const int prow = w * 16 + g * 4 + r;
#pragma unroll
      for (int dt = 0; dt < 4; ++dt)
        Op[(size_t)(q0 + prow) * Hc + dt * 16 + fr] = accO[dt][r] * inv;
    }
  }
}

extern "C" void kernel_launch(void* const* d_in, const int* in_sizes, int n_in,
                              void* d_out, int out_size, void* d_ws, size_t ws_size,
                              hipStream_t stream) {
  const float* x    = (const float*)d_in[0];
  // d_in[1] = mask: dead in reference
  const float* Wq   = (const float*)d_in[2];
  const float* bq   = (const float*)d_in[3];
  const float* Wk   = (const float*)d_in[4];
  const float* bk   = (const float*)d_in[5];
  const float* Wv   = (const float*)d_in[6];
  const float* bv   = (const float*)d_in[7];
  const float* Wo   = (const float*)d_in[8];
  const float* bo   = (const float*)d_in[9];
  const float* embK = (const float*)d_in[10];
  const float* embV = (const float*)d_in[11];
  float* out = (float*)d_out;

  const size_t MxH = (size_t)Bc * Sc * Hc;  // 4,194,304
  float* Qb = (float*)d_ws;                           // 16MB
  unsigned short* KH = (unsigned short*)(Qb + MxH);   // 8MB
  unsigned short* KL = KH + MxH;                      // 8MB
  unsigned short* VH = KL + MxH;                      // 8MB (V^T per head)
  unsigned short* VL = VH + MxH;                      // 8MB
  float* Ab = (float*)(VL + MxH);                     // 16MB  (total 64MB)

  dim3 gg(Hc / 64, (Bc * Sc) / 128);  // (16, 32)
  gemm_mfma3<0><<<gg, TPB, 0, stream>>>(x, Wq, bq, Qb, nullptr, nullptr,
                                        Bc * Sc, Hc, Hc);
  gemm_mfma3<1><<<gg, TPB, 0, stream>>>(x, Wk, bk, nullptr, KH, KL,
                                        Bc * Sc, Hc, Hc);
  gemm_mfma3<2><<<gg, TPB, 0, stream>>>(x, Wv, bv, nullptr, VH, VL,
                                        Bc * Sc, Hc, Hc);

  dim3 ga(Sc / 64, Bc * NHc);  // (16, 64)
  attn_pc<<<ga, TPA, 0, stream>>>(Qb, KH, KL, VH, VL, embK, embV, Ab);

  gemm_mfma3<0><<<gg, TPB, 0, stream>>>(Ab, Wo, bo, out, nullptr, nullptr,
                                        Bc * Sc, Hc, Hc);
}